// Round 1
// 660.633 us; speedup vs baseline: 1.3107x; 1.3107x over previous
//
#include <hip/hip_runtime.h>
#include <hip/hip_bf16.h>

#define CC 128
#define NOUT 384
#define PI_F 3.14159265358979323846f
#define RCUT 5.0f

// ---------------------------------------------------------------------------
// Dtype-agnostic loads (flags discovered on device; graph-safe).
// ---------------------------------------------------------------------------
__device__ __forceinline__ float loadF(const void* p, size_t i, int isf32) {
  if (isf32) return ((const float*)p)[i];
  unsigned int w = ((unsigned int)((const unsigned short*)p)[i]) << 16;
  return __uint_as_float(w);
}
__device__ __forceinline__ int loadI(const void* p, size_t i, int isi64) {
  if (isi64) return (int)((const long long*)p)[i];
  return ((const int*)p)[i];
}

__global__ void detect_kernel(const void* s, const void* edges, int* flags) {
  if (threadIdx.x == 0) {
    int isf32 = 0;
    const unsigned short* us = (const unsigned short*)s;
    for (int i = 0; i < 1024; i++) {
      unsigned int w = ((unsigned int)us[i]) << 16;
      float f = __uint_as_float(w);
      if (!(fabsf(f) < 1000.f)) { isf32 = 1; break; }
    }
    int isi64 = 1;
    const int* ie = (const int*)edges;
    for (int i = 1; i < 128; i += 2) {
      if (ie[i] != 0) { isi64 = 0; break; }
    }
    flags[0] = isf32;
    flags[1] = isi64;
  }
}

// ---------------------------------------------------------------------------
// CSR build: count -> scan (wave-shuffle) -> fill (writes sorted edge records)
// ---------------------------------------------------------------------------
__global__ void count_kernel(const void* __restrict__ edges, int* __restrict__ cnt,
                             const int* __restrict__ flags, int E) {
  int e = blockIdx.x * blockDim.x + threadIdx.x;
  if (e >= E) return;
  int dst = loadI(edges, (size_t)2 * e, flags[1]);
  atomicAdd(&cnt[dst], 1);
}

__global__ __launch_bounds__(1024) void scan_kernel(const int* __restrict__ cnt,
                                                    int* __restrict__ row_start,
                                                    int* __restrict__ next, int N) {
  __shared__ int woff[16];
  __shared__ int carry_sh;
  const int t = threadIdx.x;
  const int lane = t & 63;
  const int wid = t >> 6;
  if (t == 0) carry_sh = 0;
  __syncthreads();
  for (int base = 0; base < N; base += 1024) {
    int x = (base + t < N) ? cnt[base + t] : 0;
    // inclusive scan within each wave (no barriers)
    int incl = x;
    #pragma unroll
    for (int off = 1; off < 64; off <<= 1) {
      int y = __shfl_up(incl, off, 64);
      if (lane >= off) incl += y;
    }
    if (lane == 63) woff[wid] = incl;
    __syncthreads();
    // wave 0 scans the 16 wave totals -> exclusive wave offsets
    if (wid == 0 && lane < 16) {
      int w = woff[lane];
      int iw = w;
      #pragma unroll
      for (int off = 1; off < 16; off <<= 1) {
        int y = __shfl_up(iw, off, 64);
        if (lane >= off) iw += y;
      }
      woff[lane] = iw - w;
    }
    __syncthreads();
    int carry = carry_sh;
    int excl = carry + woff[wid] + incl - x;
    if (base + t < N) { row_start[base + t] = excl; next[base + t] = excl; }
    __syncthreads();
    if (t == 1023) carry_sh = excl + x;  // chunk total + old carry
    __syncthreads();
  }
  if (t == 0) row_start[N] = carry_sh;
}

// fill: scatter edges into CSR order, writing precomputed records:
//   esrc[p]  : src node id
//   efcrn[p] : {r, rn0, rn1, rn2}
//   erb[p*20..] : 20 RBF values sin((k+1)x)/r (f32, same math as before)  [PRE=1]
template <int PRE>
__global__ void fill_kernel(const void* __restrict__ edges,
                            const void* __restrict__ r_ij,
                            const void* __restrict__ rn,
                            int* __restrict__ next,
                            int* __restrict__ esrc,
                            float4* __restrict__ efcrn,
                            float* __restrict__ erb,
                            const int* __restrict__ flags, int E) {
  int e = blockIdx.x * blockDim.x + threadIdx.x;
  if (e >= E) return;
  const int isi64 = flags[1];
  const int isf32 = flags[0];
  const int dst = loadI(edges, (size_t)2 * e, isi64);
  const int src = loadI(edges, (size_t)2 * e + 1, isi64);
  const float r  = loadF(r_ij, e, isf32);
  const float r0 = loadF(rn, (size_t)e * 3 + 0, isf32);
  const float r1 = loadF(rn, (size_t)e * 3 + 1, isf32);
  const float r2 = loadF(rn, (size_t)e * 3 + 2, isf32);
  const int p = atomicAdd(&next[dst], 1);
  esrc[p] = src;
  efcrn[p] = make_float4(r, r0, r1, r2);
  if (PRE) {
    const float x = (PI_F / RCUT) * r;
    const float s1 = __sinf(x);
    const float c1 = __cosf(x);
    const float rinv = __builtin_amdgcn_rcpf(r);
    const float twoc = 2.f * c1;
    float sp = 0.f, sn = s1;
    float rbv[20];
    #pragma unroll
    for (int k = 0; k < 20; k++) {
      rbv[k] = sn * rinv;
      const float s2 = twoc * sn - sp;
      sp = sn; sn = s2;
    }
    float4* rb4 = (float4*)(erb + (size_t)p * 20);
    #pragma unroll
    for (int j = 0; j < 5; j++)
      rb4[j] = make_float4(rbv[4 * j], rbv[4 * j + 1], rbv[4 * j + 2], rbv[4 * j + 3]);
  }
}

// ---------------------------------------------------------------------------
// Node MLP: s_pass = silu(s@W1+b1)@W2+b2  (bf16 out); 8 nodes/block.
// Dtype-specialized at compile time (uniform branch at kernel entry).
// ---------------------------------------------------------------------------
template <int ISF32>
__device__ __forceinline__ void node_mlp_body(
    const void* __restrict__ s,
    const void* __restrict__ W1, const void* __restrict__ b1,
    const void* __restrict__ W2, const void* __restrict__ b2,
    __hip_bfloat16* __restrict__ s_pass, int N) {
  const int M = 8;
  __shared__ float s_sh[M][CC];
  __shared__ float h_sh[M][CC];
  const int c = threadIdx.x;
  const int n0 = blockIdx.x * M;

  #pragma unroll
  for (int m = 0; m < M; m++) {
    int n = n0 + m;
    s_sh[m][c] = (n < N) ? loadF(s, (size_t)n * CC + c, ISF32) : 0.f;
  }
  __syncthreads();

  float acc[M];
  #pragma unroll
  for (int m = 0; m < M; m++) acc[m] = 0.f;
  for (int k = 0; k < CC; k++) {
    float w = loadF(W1, (size_t)k * CC + c, ISF32);
    #pragma unroll
    for (int m = 0; m < M; m++) acc[m] += s_sh[m][k] * w;
  }
  float bb1 = loadF(b1, c, ISF32);
  #pragma unroll
  for (int m = 0; m < M; m++) {
    float x = acc[m] + bb1;
    h_sh[m][c] = x / (1.f + __expf(-x));
  }
  __syncthreads();

  #pragma unroll
  for (int jj = 0; jj < 3; jj++) {
    int j = jj * CC + c;
    float a2[M];
    #pragma unroll
    for (int m = 0; m < M; m++) a2[m] = 0.f;
    for (int k = 0; k < CC; k++) {
      float w = loadF(W2, (size_t)k * NOUT + j, ISF32);
      #pragma unroll
      for (int m = 0; m < M; m++) a2[m] += h_sh[m][k] * w;
    }
    float bb2 = loadF(b2, j, ISF32);
    #pragma unroll
    for (int m = 0; m < M; m++) {
      int n = n0 + m;
      if (n < N) s_pass[(size_t)n * NOUT + j] = __float2bfloat16(a2[m] + bb2);
    }
  }
}

__global__ __launch_bounds__(128) void node_mlp_kernel(
    const void* __restrict__ s,
    const void* __restrict__ W1, const void* __restrict__ b1,
    const void* __restrict__ W2, const void* __restrict__ b2,
    __hip_bfloat16* __restrict__ s_pass, const int* __restrict__ flags, int N) {
  if (flags[0]) node_mlp_body<1>(s, W1, b1, W2, b2, s_pass, N);
  else          node_mlp_body<0>(s, W1, b1, W2, b2, s_pass, N);
}

// ---------------------------------------------------------------------------
// Per-node gather-aggregate: one block per dst node, 128 threads = channels.
// Reads precomputed sorted edge records (one indirection level, not three);
// RBF recurrence removed from the hot loop when PRE=1.
// ---------------------------------------------------------------------------
template <int ISF32, int PRE>
__device__ __forceinline__ void agg_body(
    const void* __restrict__ s, const void* __restrict__ v,
    const void* __restrict__ Wr, const void* __restrict__ br,
    const __hip_bfloat16* __restrict__ s_pass,
    const int* __restrict__ row_start,
    const int* __restrict__ esrc, const float4* __restrict__ efcrn,
    const float* __restrict__ erb,
    void* __restrict__ out, int N) {
  const int n = blockIdx.x;
  const int c = threadIdx.x;

  // Hoist Wr columns for this channel (kept resident: launch_bounds allows it).
  float w0[20], w1[20], w2[20];
  #pragma unroll
  for (int k = 0; k < 20; k++) {
    w0[k] = loadF(Wr, (size_t)k * NOUT + c, ISF32);
    w1[k] = loadF(Wr, (size_t)k * NOUT + CC + c, ISF32);
    w2[k] = loadF(Wr, (size_t)k * NOUT + 2 * CC + c, ISF32);
  }
  const float b0  = loadF(br, c, ISF32);
  const float b1v = loadF(br, CC + c, ISF32);
  const float b2v = loadF(br, 2 * CC + c, ISF32);

  float accs = 0.f, av0 = 0.f, av1 = 0.f, av2 = 0.f;
  const int beg = row_start[n], end = row_start[n + 1];
  for (int i = beg; i < end; ++i) {
    const int src = esrc[i];            // first load gates the gathers directly
    const float4 fr = efcrn[i];         // {r, rn0, rn1, rn2}
    const size_t sb = (size_t)src * NOUT;

    // gathers issue early, independent of the dot-product below
    const float sp0 = __bfloat162float(s_pass[sb + c]);
    const float sp1 = __bfloat162float(s_pass[sb + CC + c]);
    const float sp2 = __bfloat162float(s_pass[sb + 2 * CC + c]);
    float vv0, vv1, vv2;
    if (ISF32) {
      const float* vf = (const float*)v;
      vv0 = vf[sb + c];
      vv1 = vf[sb + CC + c];
      vv2 = vf[sb + 2 * CC + c];
    } else {
      const unsigned short* vb = (const unsigned short*)v;
      vv0 = __uint_as_float(((unsigned int)vb[sb + c]) << 16);
      vv1 = __uint_as_float(((unsigned int)vb[sb + CC + c]) << 16);
      vv2 = __uint_as_float(((unsigned int)vb[sb + 2 * CC + c]) << 16);
    }

    const float fc = 0.5f * (__cosf((PI_F / RCUT) * fr.x) + 1.f);

    float a0 = b0, a1 = b1v, a2 = b2v;
    if (PRE) {
      const float4* rb4 = (const float4*)(erb + (size_t)i * 20);
      #pragma unroll
      for (int j = 0; j < 5; j++) {
        const float4 rb = rb4[j];
        a0 += rb.x * w0[4 * j];     a1 += rb.x * w1[4 * j];     a2 += rb.x * w2[4 * j];
        a0 += rb.y * w0[4 * j + 1]; a1 += rb.y * w1[4 * j + 1]; a2 += rb.y * w2[4 * j + 1];
        a0 += rb.z * w0[4 * j + 2]; a1 += rb.z * w1[4 * j + 2]; a2 += rb.z * w2[4 * j + 2];
        a0 += rb.w * w0[4 * j + 3]; a1 += rb.w * w1[4 * j + 3]; a2 += rb.w * w2[4 * j + 3];
      }
    } else {
      const float x = (PI_F / RCUT) * fr.x;
      const float s1 = __sinf(x);
      const float c1 = __cosf(x);
      const float rinv = __builtin_amdgcn_rcpf(fr.x);
      const float twoc = 2.f * c1;
      float sp = 0.f, sn = s1;
      #pragma unroll
      for (int k = 0; k < 20; k++) {
        const float rb = sn * rinv;
        a0 += rb * w0[k]; a1 += rb * w1[k]; a2 += rb * w2[k];
        const float s2 = twoc * sn - sp;
        sp = sn; sn = s2;
      }
    }

    const float p0 = a0 * fc * sp0;
    const float p1 = a1 * fc * sp1;
    const float p2 = a2 * fc * sp2;
    accs += p1;
    av0 += vv0 * p0 + fr.y * p2;
    av1 += vv1 * p0 + fr.z * p2;
    av2 += vv2 * p0 + fr.w * p2;
  }

  const size_t si = (size_t)n * CC + c;
  const size_t vi = (size_t)n * NOUT;
  const float so = loadF(s, si, ISF32) + accs;
  float o0, o1, o2;
  if (ISF32) {
    const float* vf = (const float*)v;
    o0 = vf[vi + 0 * CC + c] + av0;
    o1 = vf[vi + 1 * CC + c] + av1;
    o2 = vf[vi + 2 * CC + c] + av2;
  } else {
    const unsigned short* vb = (const unsigned short*)v;
    o0 = __uint_as_float(((unsigned int)vb[vi + 0 * CC + c]) << 16) + av0;
    o1 = __uint_as_float(((unsigned int)vb[vi + 1 * CC + c]) << 16) + av1;
    o2 = __uint_as_float(((unsigned int)vb[vi + 2 * CC + c]) << 16) + av2;
  }
  const size_t vo = (size_t)N * CC + vi;
  if (ISF32) {
    float* o = (float*)out;
    o[si] = so;
    o[vo + 0 * CC + c] = o0;
    o[vo + 1 * CC + c] = o1;
    o[vo + 2 * CC + c] = o2;
  } else {
    __hip_bfloat16* o = (__hip_bfloat16*)out;
    o[si] = __float2bfloat16(so);
    o[vo + 0 * CC + c] = __float2bfloat16(o0);
    o[vo + 1 * CC + c] = __float2bfloat16(o1);
    o[vo + 2 * CC + c] = __float2bfloat16(o2);
  }
}

template <int PRE>
__global__ __launch_bounds__(128, 3) void aggregate_kernel(
    const void* __restrict__ s, const void* __restrict__ v,
    const void* __restrict__ Wr, const void* __restrict__ br,
    const __hip_bfloat16* __restrict__ s_pass,
    const int* __restrict__ row_start,
    const int* __restrict__ esrc, const float4* __restrict__ efcrn,
    const float* __restrict__ erb,
    void* __restrict__ out, const int* __restrict__ flags, int N) {
  if (flags[0]) agg_body<1, PRE>(s, v, Wr, br, s_pass, row_start, esrc, efcrn, erb, out, N);
  else          agg_body<0, PRE>(s, v, Wr, br, s_pass, row_start, esrc, efcrn, erb, out, N);
}

extern "C" void kernel_launch(void* const* d_in, const int* in_sizes, int n_in,
                              void* d_out, int out_size, void* d_ws, size_t ws_size,
                              hipStream_t stream) {
  const void* s     = d_in[0];
  const void* v     = d_in[1];
  const void* edges = d_in[2];
  const void* r_ij  = d_in[3];
  const void* rn    = d_in[4];
  const void* W1    = d_in[5];
  const void* b1    = d_in[6];
  const void* W2    = d_in[7];
  const void* b2    = d_in[8];
  const void* Wr    = d_in[9];
  const void* br    = d_in[10];

  const int N = in_sizes[0] / CC;     // 50000
  const int E = in_sizes[3];          // 400000

  // ws layout: flags | s_pass | efcrn | esrc | cnt | row_start | next | erb
  char* ws = (char*)d_ws;
  int* flags = (int*)ws;
  size_t off = 256;
  __hip_bfloat16* s_pass = (__hip_bfloat16*)(ws + off);
  off += (size_t)N * NOUT * sizeof(__hip_bfloat16);
  float4* efcrn = (float4*)(ws + off);   off += (size_t)E * sizeof(float4);
  int* esrc      = (int*)(ws + off);     off += (size_t)E * sizeof(int);
  int* cnt       = (int*)(ws + off);     off += (size_t)N * sizeof(int);
  int* row_start = (int*)(ws + off);     off += (size_t)(N + 1) * sizeof(int);
  int* next      = (int*)(ws + off);     off += (size_t)N * sizeof(int);
  off = (off + 15) & ~(size_t)15;
  float* erb = (float*)(ws + off);
  const size_t need_pre = off + (size_t)E * 20 * sizeof(float);
  const int pre = (ws_size >= need_pre) ? 1 : 0;

  hipMemsetAsync(cnt, 0, (size_t)N * sizeof(int), stream);

  detect_kernel<<<1, 64, 0, stream>>>(s, edges, flags);
  count_kernel<<<(E + 255) / 256, 256, 0, stream>>>(edges, cnt, flags, E);
  scan_kernel<<<1, 1024, 0, stream>>>(cnt, row_start, next, N);
  if (pre)
    fill_kernel<1><<<(E + 255) / 256, 256, 0, stream>>>(edges, r_ij, rn, next,
                                                        esrc, efcrn, erb, flags, E);
  else
    fill_kernel<0><<<(E + 255) / 256, 256, 0, stream>>>(edges, r_ij, rn, next,
                                                        esrc, efcrn, erb, flags, E);
  node_mlp_kernel<<<(N + 7) / 8, 128, 0, stream>>>(s, W1, b1, W2, b2, s_pass,
                                                   flags, N);
  if (pre)
    aggregate_kernel<1><<<N, 128, 0, stream>>>(s, v, Wr, br, s_pass, row_start,
                                               esrc, efcrn, erb, d_out, flags, N);
  else
    aggregate_kernel<0><<<N, 128, 0, stream>>>(s, v, Wr, br, s_pass, row_start,
                                               esrc, efcrn, erb, d_out, flags, N);
}

// Round 3
// 638.301 us; speedup vs baseline: 1.3566x; 1.0350x over previous
//
#include <hip/hip_runtime.h>
#include <hip/hip_bf16.h>

#define CC 128
#define NOUT 384
#define PI_F 3.14159265358979323846f
#define RCUT 5.0f

typedef float f32x2 __attribute__((ext_vector_type(2)));

// ---------------------------------------------------------------------------
// Dtype-agnostic loads (flags discovered on device; graph-safe).
// ---------------------------------------------------------------------------
__device__ __forceinline__ float loadF(const void* p, size_t i, int isf32) {
  if (isf32) return ((const float*)p)[i];
  unsigned int w = ((unsigned int)((const unsigned short*)p)[i]) << 16;
  return __uint_as_float(w);
}
__device__ __forceinline__ int loadI(const void* p, size_t i, int isi64) {
  if (isi64) return (int)((const long long*)p)[i];
  return ((const int*)p)[i];
}
__device__ __forceinline__ unsigned int bfbits(float f) {
  __hip_bfloat16 h = __float2bfloat16(f);
  unsigned short u;
  __builtin_memcpy(&u, &h, 2);
  return (unsigned int)u;
}
__device__ __forceinline__ unsigned int bfpack(float lo, float hi) {
  return bfbits(lo) | (bfbits(hi) << 16);
}
__device__ __forceinline__ float bf16lo(unsigned int u) {
  return __uint_as_float(u << 16);
}
__device__ __forceinline__ float bf16hi(unsigned int u) {
  return __uint_as_float(u & 0xffff0000u);
}

// Round-1 (known-passing) serial detect.
__global__ void detect_kernel(const void* s, const void* edges, int* flags) {
  if (threadIdx.x == 0) {
    int isf32 = 0;
    const unsigned short* us = (const unsigned short*)s;
    for (int i = 0; i < 1024; i++) {
      unsigned int w = ((unsigned int)us[i]) << 16;
      float f = __uint_as_float(w);
      if (!(fabsf(f) < 1000.f)) { isf32 = 1; break; }
    }
    int isi64 = 1;
    const int* ie = (const int*)edges;
    for (int i = 1; i < 128; i += 2) {
      if (ie[i] != 0) { isi64 = 0; break; }
    }
    flags[0] = isf32;
    flags[1] = isi64;
  }
}

// ---------------------------------------------------------------------------
// CSR build: count -> scan (round-1 wave-shuffle version, known-passing) -> fill
// ---------------------------------------------------------------------------
__global__ void count_kernel(const void* __restrict__ edges, int* __restrict__ cnt,
                             const int* __restrict__ flags, int E) {
  int e = blockIdx.x * blockDim.x + threadIdx.x;
  if (e >= E) return;
  int dst = loadI(edges, (size_t)2 * e, flags[1]);
  atomicAdd(&cnt[dst], 1);
}

__global__ __launch_bounds__(1024) void scan_kernel(const int* __restrict__ cnt,
                                                    int* __restrict__ row_start,
                                                    int* __restrict__ next, int N) {
  __shared__ int woff[16];
  __shared__ int carry_sh;
  const int t = threadIdx.x;
  const int lane = t & 63;
  const int wid = t >> 6;
  if (t == 0) carry_sh = 0;
  __syncthreads();
  for (int base = 0; base < N; base += 1024) {
    int x = (base + t < N) ? cnt[base + t] : 0;
    int incl = x;
    #pragma unroll
    for (int off = 1; off < 64; off <<= 1) {
      int y = __shfl_up(incl, off, 64);
      if (lane >= off) incl += y;
    }
    if (lane == 63) woff[wid] = incl;
    __syncthreads();
    if (wid == 0 && lane < 16) {
      int w = woff[lane];
      int iw = w;
      #pragma unroll
      for (int off = 1; off < 16; off <<= 1) {
        int y = __shfl_up(iw, off, 64);
        if (lane >= off) iw += y;
      }
      woff[lane] = iw - w;
    }
    __syncthreads();
    int carry = carry_sh;
    int excl = carry + woff[wid] + incl - x;
    if (base + t < N) { row_start[base + t] = excl; next[base + t] = excl; }
    __syncthreads();
    if (t == 1023) carry_sh = excl + x;
    __syncthreads();
  }
  if (t == 0) row_start[N] = carry_sh;
}

// fill: scatter edges into CSR order; records:
//   esrc[p]  : src node id
//   efcrn[p] : {fc (PRE=1) or r (PRE=0), rn0, rn1, rn2}
//   erb[p*20..] : 20 values fc*sin((k+1)x)/r  (f32; PRE=1 only)
template <int PRE>
__global__ void fill_kernel(const void* __restrict__ edges,
                            const void* __restrict__ r_ij,
                            const void* __restrict__ rn,
                            int* __restrict__ next,
                            int* __restrict__ esrc,
                            float4* __restrict__ efcrn,
                            float* __restrict__ erb,
                            const int* __restrict__ flags, int E) {
  int e = blockIdx.x * blockDim.x + threadIdx.x;
  if (e >= E) return;
  const int isi64 = flags[1];
  const int isf32 = flags[0];
  const int dst = loadI(edges, (size_t)2 * e, isi64);
  const int src = loadI(edges, (size_t)2 * e + 1, isi64);
  const float r  = loadF(r_ij, e, isf32);
  const float r0 = loadF(rn, (size_t)e * 3 + 0, isf32);
  const float r1 = loadF(rn, (size_t)e * 3 + 1, isf32);
  const float r2 = loadF(rn, (size_t)e * 3 + 2, isf32);
  const int p = atomicAdd(&next[dst], 1);
  esrc[p] = src;
  if (PRE) {
    const float x = (PI_F / RCUT) * r;
    const float s1 = __sinf(x);
    const float c1 = __cosf(x);
    const float fc = 0.5f * (c1 + 1.f);
    efcrn[p] = make_float4(fc, r0, r1, r2);
    const float rf = __builtin_amdgcn_rcpf(r) * fc;
    const float twoc = 2.f * c1;
    float sp = 0.f, sn = s1;
    float rbv[20];
    #pragma unroll
    for (int k = 0; k < 20; k++) {
      rbv[k] = sn * rf;
      const float s2 = twoc * sn - sp;
      sp = sn; sn = s2;
    }
    float4* rb4 = (float4*)(erb + (size_t)p * 20);
    #pragma unroll
    for (int j = 0; j < 5; j++)
      rb4[j] = make_float4(rbv[4 * j], rbv[4 * j + 1], rbv[4 * j + 2], rbv[4 * j + 3]);
  } else {
    efcrn[p] = make_float4(r, r0, r1, r2);
  }
}

// ---------------------------------------------------------------------------
// Node MLP: s_pass = silu(s@W1+b1)@W2+b2; writes packed gather table:
//   tabA[n*CC+c] = {bf16(sp0)|bf16(sp1)<<16, bf16(sp2)|bf16(v0)<<16}
// ---------------------------------------------------------------------------
template <int ISF32>
__device__ __forceinline__ void node_mlp_body(
    const void* __restrict__ s, const void* __restrict__ v,
    const void* __restrict__ W1, const void* __restrict__ b1,
    const void* __restrict__ W2, const void* __restrict__ b2,
    uint2* __restrict__ tabA, int N) {
  const int M = 8;
  __shared__ float s_sh[M][CC];
  __shared__ float h_sh[M][CC];
  const int c = threadIdx.x;
  const int n0 = blockIdx.x * M;

  #pragma unroll
  for (int m = 0; m < M; m++) {
    int n = n0 + m;
    s_sh[m][c] = (n < N) ? loadF(s, (size_t)n * CC + c, ISF32) : 0.f;
  }
  __syncthreads();

  float acc[M];
  #pragma unroll
  for (int m = 0; m < M; m++) acc[m] = 0.f;
  for (int k = 0; k < CC; k++) {
    float w = loadF(W1, (size_t)k * CC + c, ISF32);
    #pragma unroll
    for (int m = 0; m < M; m++) acc[m] += s_sh[m][k] * w;
  }
  float bb1 = loadF(b1, c, ISF32);
  #pragma unroll
  for (int m = 0; m < M; m++) {
    float x = acc[m] + bb1;
    h_sh[m][c] = x / (1.f + __expf(-x));
  }
  __syncthreads();

  float a2s[3][M];
  #pragma unroll
  for (int jj = 0; jj < 3; jj++) {
    int j = jj * CC + c;
    float a2[M];
    #pragma unroll
    for (int m = 0; m < M; m++) a2[m] = 0.f;
    for (int k = 0; k < CC; k++) {
      float w = loadF(W2, (size_t)k * NOUT + j, ISF32);
      #pragma unroll
      for (int m = 0; m < M; m++) a2[m] += h_sh[m][k] * w;
    }
    float bb2 = loadF(b2, j, ISF32);
    #pragma unroll
    for (int m = 0; m < M; m++) a2s[jj][m] = a2[m] + bb2;
  }

  #pragma unroll
  for (int m = 0; m < M; m++) {
    int n = n0 + m;
    if (n >= N) continue;
    const float v0 = loadF(v, (size_t)n * NOUT + c, ISF32);
    const size_t tix = (size_t)n * CC + c;
    tabA[tix] = make_uint2(bfpack(a2s[0][m], a2s[1][m]), bfpack(a2s[2][m], v0));
  }
}

__global__ __launch_bounds__(128) void node_mlp_kernel(
    const void* __restrict__ s, const void* __restrict__ v,
    const void* __restrict__ W1, const void* __restrict__ b1,
    const void* __restrict__ W2, const void* __restrict__ b2,
    uint2* __restrict__ tabA, const int* __restrict__ flags, int N) {
  if (flags[0]) node_mlp_body<1>(s, v, W1, b1, W2, b2, tabA, N);
  else          node_mlp_body<0>(s, v, W1, b1, W2, b2, tabA, N);
}

// ---------------------------------------------------------------------------
// Per-node gather-aggregate.  One block per dst node, 128 threads = channels.
// Plain C only (no inline asm).  Edge loop unrolled by 2 so each (possibly
// rematerialized) weight load feeds two edges' FMAs; f32x2 math lets the
// backend use v_pk_fma_f32 on its own.
// ---------------------------------------------------------------------------
template <int ISF32, int PRE>
__device__ __forceinline__ void agg_body(
    const void* __restrict__ s, const void* __restrict__ v,
    const void* __restrict__ Wr, const void* __restrict__ br,
    const uint2* __restrict__ tabA,
    const int* __restrict__ row_start,
    const int* __restrict__ esrc, const float4* __restrict__ efcrn,
    const float* __restrict__ erb,
    void* __restrict__ out, int N) {
  const int n = blockIdx.x;
  const int c = threadIdx.x;

  f32x2 w0p[10], w1p[10], w2p[10];
  #pragma unroll
  for (int j = 0; j < 10; j++) {
    w0p[j] = f32x2{loadF(Wr, (size_t)(2 * j) * NOUT + c, ISF32),
                   loadF(Wr, (size_t)(2 * j + 1) * NOUT + c, ISF32)};
    w1p[j] = f32x2{loadF(Wr, (size_t)(2 * j) * NOUT + CC + c, ISF32),
                   loadF(Wr, (size_t)(2 * j + 1) * NOUT + CC + c, ISF32)};
    w2p[j] = f32x2{loadF(Wr, (size_t)(2 * j) * NOUT + 2 * CC + c, ISF32),
                   loadF(Wr, (size_t)(2 * j + 1) * NOUT + 2 * CC + c, ISF32)};
  }
  const float b0  = loadF(br, c, ISF32);
  const float b1v = loadF(br, CC + c, ISF32);
  const float b2v = loadF(br, 2 * CC + c, ISF32);

  float accs = 0.f, av0 = 0.f, av1 = 0.f, av2 = 0.f;
  const int beg = row_start[n], end = row_start[n + 1];

  int i = beg;
  for (; i + 2 <= end; i += 2) {
    const int srcA = esrc[i];
    const int srcB = esrc[i + 1];
    const float4 frA = efcrn[i];
    const float4 frB = efcrn[i + 1];
    const uint2 taA = tabA[(size_t)srcA * CC + c];
    const uint2 taB = tabA[(size_t)srcB * CC + c];
    const float v1A = loadF(v, (size_t)srcA * NOUT + CC + c, ISF32);
    const float v2A = loadF(v, (size_t)srcA * NOUT + 2 * CC + c, ISF32);
    const float v1B = loadF(v, (size_t)srcB * NOUT + CC + c, ISF32);
    const float v2B = loadF(v, (size_t)srcB * NOUT + 2 * CC + c, ISF32);

    float fcA, fcB;
    f32x2 rbA[10], rbB[10];
    if (PRE) {
      fcA = frA.x;
      fcB = frB.x;
      const f32x2* rpA = (const f32x2*)(erb + (size_t)i * 20);
      const f32x2* rpB = (const f32x2*)(erb + (size_t)(i + 1) * 20);
      #pragma unroll
      for (int j = 0; j < 10; j++) { rbA[j] = rpA[j]; rbB[j] = rpB[j]; }
    } else {
      const float xA = (PI_F / RCUT) * frA.x;
      const float s1A = __sinf(xA), c1A = __cosf(xA);
      fcA = 0.5f * (c1A + 1.f);
      const float rfA = __builtin_amdgcn_rcpf(frA.x) * fcA;
      const float twocA = 2.f * c1A;
      const float xB = (PI_F / RCUT) * frB.x;
      const float s1B = __sinf(xB), c1B = __cosf(xB);
      fcB = 0.5f * (c1B + 1.f);
      const float rfB = __builtin_amdgcn_rcpf(frB.x) * fcB;
      const float twocB = 2.f * c1B;
      float spA = 0.f, snA = s1A, spB = 0.f, snB = s1B;
      #pragma unroll
      for (int j = 0; j < 10; j++) {
        const float qA0 = snA * rfA;
        float s2 = twocA * snA - spA; spA = snA; snA = s2;
        const float qA1 = snA * rfA;
        s2 = twocA * snA - spA; spA = snA; snA = s2;
        rbA[j] = f32x2{qA0, qA1};
        const float qB0 = snB * rfB;
        s2 = twocB * snB - spB; spB = snB; snB = s2;
        const float qB1 = snB * rfB;
        s2 = twocB * snB - spB; spB = snB; snB = s2;
        rbB[j] = f32x2{qB0, qB1};
      }
    }

    f32x2 a0A = f32x2{0.f, 0.f}, a1A = a0A, a2A = a0A;
    f32x2 a0B = a0A, a1B = a0A, a2B = a0A;
    #pragma unroll
    for (int j = 0; j < 10; j++) {
      a0A += rbA[j] * w0p[j];  a0B += rbB[j] * w0p[j];
      a1A += rbA[j] * w1p[j];  a1B += rbB[j] * w1p[j];
      a2A += rbA[j] * w2p[j];  a2B += rbB[j] * w2p[j];
    }

    const float a0Af = fmaf(b0,  fcA, a0A.x + a0A.y);
    const float a1Af = fmaf(b1v, fcA, a1A.x + a1A.y);
    const float a2Af = fmaf(b2v, fcA, a2A.x + a2A.y);
    const float p0A = a0Af * bf16lo(taA.x);
    const float p1A = a1Af * bf16hi(taA.x);
    const float p2A = a2Af * bf16lo(taA.y);
    accs += p1A;
    av0 = fmaf(bf16hi(taA.y), p0A, fmaf(frA.y, p2A, av0));
    av1 = fmaf(v1A, p0A, fmaf(frA.z, p2A, av1));
    av2 = fmaf(v2A, p0A, fmaf(frA.w, p2A, av2));

    const float a0Bf = fmaf(b0,  fcB, a0B.x + a0B.y);
    const float a1Bf = fmaf(b1v, fcB, a1B.x + a1B.y);
    const float a2Bf = fmaf(b2v, fcB, a2B.x + a2B.y);
    const float p0B = a0Bf * bf16lo(taB.x);
    const float p1B = a1Bf * bf16hi(taB.x);
    const float p2B = a2Bf * bf16lo(taB.y);
    accs += p1B;
    av0 = fmaf(bf16hi(taB.y), p0B, fmaf(frB.y, p2B, av0));
    av1 = fmaf(v1B, p0B, fmaf(frB.z, p2B, av1));
    av2 = fmaf(v2B, p0B, fmaf(frB.w, p2B, av2));
  }

  for (; i < end; ++i) {
    const int src = esrc[i];
    const float4 fr = efcrn[i];
    const uint2 ta = tabA[(size_t)src * CC + c];
    const float v1f = loadF(v, (size_t)src * NOUT + CC + c, ISF32);
    const float v2f = loadF(v, (size_t)src * NOUT + 2 * CC + c, ISF32);

    float fc;
    f32x2 rb[10];
    if (PRE) {
      fc = fr.x;
      const f32x2* rp = (const f32x2*)(erb + (size_t)i * 20);
      #pragma unroll
      for (int j = 0; j < 10; j++) rb[j] = rp[j];
    } else {
      const float x = (PI_F / RCUT) * fr.x;
      const float s1 = __sinf(x), c1 = __cosf(x);
      fc = 0.5f * (c1 + 1.f);
      const float rf = __builtin_amdgcn_rcpf(fr.x) * fc;
      const float twoc = 2.f * c1;
      float spv = 0.f, snv = s1;
      #pragma unroll
      for (int j = 0; j < 10; j++) {
        const float q0 = snv * rf;
        float s2 = twoc * snv - spv; spv = snv; snv = s2;
        const float q1 = snv * rf;
        s2 = twoc * snv - spv; spv = snv; snv = s2;
        rb[j] = f32x2{q0, q1};
      }
    }

    f32x2 a0p = f32x2{0.f, 0.f}, a1p = a0p, a2p = a0p;
    #pragma unroll
    for (int j = 0; j < 10; j++) {
      a0p += rb[j] * w0p[j];
      a1p += rb[j] * w1p[j];
      a2p += rb[j] * w2p[j];
    }

    const float a0 = fmaf(b0,  fc, a0p.x + a0p.y);
    const float a1 = fmaf(b1v, fc, a1p.x + a1p.y);
    const float a2 = fmaf(b2v, fc, a2p.x + a2p.y);
    const float p0 = a0 * bf16lo(ta.x);
    const float p1 = a1 * bf16hi(ta.x);
    const float p2 = a2 * bf16lo(ta.y);
    accs += p1;
    av0 = fmaf(bf16hi(ta.y), p0, fmaf(fr.y, p2, av0));
    av1 = fmaf(v1f, p0, fmaf(fr.z, p2, av1));
    av2 = fmaf(v2f, p0, fmaf(fr.w, p2, av2));
  }

  const size_t si = (size_t)n * CC + c;
  const size_t vi = (size_t)n * NOUT;
  const float so = loadF(s, si, ISF32) + accs;
  const float o0 = loadF(v, vi + 0 * CC + c, ISF32) + av0;
  const float o1 = loadF(v, vi + 1 * CC + c, ISF32) + av1;
  const float o2 = loadF(v, vi + 2 * CC + c, ISF32) + av2;
  const size_t vo = (size_t)N * CC + vi;
  if (ISF32) {
    float* o = (float*)out;
    o[si] = so;
    o[vo + 0 * CC + c] = o0;
    o[vo + 1 * CC + c] = o1;
    o[vo + 2 * CC + c] = o2;
  } else {
    __hip_bfloat16* o = (__hip_bfloat16*)out;
    o[si] = __float2bfloat16(so);
    o[vo + 0 * CC + c] = __float2bfloat16(o0);
    o[vo + 1 * CC + c] = __float2bfloat16(o1);
    o[vo + 2 * CC + c] = __float2bfloat16(o2);
  }
}

template <int PRE>
__global__ __launch_bounds__(128, 3) void aggregate_kernel(
    const void* __restrict__ s, const void* __restrict__ v,
    const void* __restrict__ Wr, const void* __restrict__ br,
    const uint2* __restrict__ tabA,
    const int* __restrict__ row_start,
    const int* __restrict__ esrc, const float4* __restrict__ efcrn,
    const float* __restrict__ erb,
    void* __restrict__ out, const int* __restrict__ flags, int N) {
  if (flags[0]) agg_body<1, PRE>(s, v, Wr, br, tabA, row_start, esrc, efcrn, erb, out, N);
  else          agg_body<0, PRE>(s, v, Wr, br, tabA, row_start, esrc, efcrn, erb, out, N);
}

extern "C" void kernel_launch(void* const* d_in, const int* in_sizes, int n_in,
                              void* d_out, int out_size, void* d_ws, size_t ws_size,
                              hipStream_t stream) {
  const void* s     = d_in[0];
  const void* v     = d_in[1];
  const void* edges = d_in[2];
  const void* r_ij  = d_in[3];
  const void* rn    = d_in[4];
  const void* W1    = d_in[5];
  const void* b1    = d_in[6];
  const void* W2    = d_in[7];
  const void* b2    = d_in[8];
  const void* Wr    = d_in[9];
  const void* br    = d_in[10];

  const int N = in_sizes[0] / CC;     // 50000
  const int E = in_sizes[3];          // 400000

  // ws: flags | tabA | efcrn | esrc | cnt | row_start | next | erb
  char* ws = (char*)d_ws;
  int* flags = (int*)ws;
  size_t off = 256;
  auto align16 = [](size_t x) { return (x + 15) & ~(size_t)15; };
  uint2* tabA = (uint2*)(ws + off);      off += align16((size_t)N * CC * 8);
  float4* efcrn = (float4*)(ws + off);   off += align16((size_t)E * 16);
  int* esrc = (int*)(ws + off);          off += align16((size_t)E * 4);
  int* cnt = (int*)(ws + off);           off += align16((size_t)N * 4);
  int* row_start = (int*)(ws + off);     off += align16((size_t)(N + 1) * 4);
  int* next = (int*)(ws + off);          off += align16((size_t)N * 4);
  float* erb = (float*)(ws + off);
  const size_t off_erb_end = off + (size_t)E * 20 * 4;
  const int pre = (ws_size >= off_erb_end) ? 1 : 0;

  hipMemsetAsync(cnt, 0, (size_t)N * sizeof(int), stream);

  detect_kernel<<<1, 64, 0, stream>>>(s, edges, flags);
  count_kernel<<<(E + 255) / 256, 256, 0, stream>>>(edges, cnt, flags, E);
  scan_kernel<<<1, 1024, 0, stream>>>(cnt, row_start, next, N);
  if (pre)
    fill_kernel<1><<<(E + 255) / 256, 256, 0, stream>>>(edges, r_ij, rn, next,
                                                        esrc, efcrn, erb, flags, E);
  else
    fill_kernel<0><<<(E + 255) / 256, 256, 0, stream>>>(edges, r_ij, rn, next,
                                                        esrc, efcrn, erb, flags, E);
  node_mlp_kernel<<<(N + 7) / 8, 128, 0, stream>>>(s, v, W1, b1, W2, b2,
                                                   tabA, flags, N);
  if (pre)
    aggregate_kernel<1><<<N, 128, 0, stream>>>(s, v, Wr, br, tabA, row_start,
                                               esrc, efcrn, erb, d_out, flags, N);
  else
    aggregate_kernel<0><<<N, 128, 0, stream>>>(s, v, Wr, br, tabA, row_start,
                                               esrc, efcrn, erb, d_out, flags, N);
}

// Round 4
// 611.790 us; speedup vs baseline: 1.4154x; 1.0433x over previous
//
#include <hip/hip_runtime.h>
#include <hip/hip_bf16.h>

#define CC 128
#define NOUT 384
#define PI_F 3.14159265358979323846f
#define RCUT 5.0f

typedef float f32x2 __attribute__((ext_vector_type(2)));
typedef __attribute__((ext_vector_type(8))) short bf16x8;
typedef __attribute__((ext_vector_type(4))) float f32x4;

// ---------------------------------------------------------------------------
// Dtype-agnostic loads (flags discovered on device; graph-safe).
// ---------------------------------------------------------------------------
__device__ __forceinline__ float loadF(const void* p, size_t i, int isf32) {
  if (isf32) return ((const float*)p)[i];
  unsigned int w = ((unsigned int)((const unsigned short*)p)[i]) << 16;
  return __uint_as_float(w);
}
__device__ __forceinline__ int loadI(const void* p, size_t i, int isi64) {
  if (isi64) return (int)((const long long*)p)[i];
  return ((const int*)p)[i];
}
__device__ __forceinline__ unsigned int bfbits(float f) {
  __hip_bfloat16 h = __float2bfloat16(f);
  unsigned short u;
  __builtin_memcpy(&u, &h, 2);
  return (unsigned int)u;
}
__device__ __forceinline__ unsigned int bfpack(float lo, float hi) {
  return bfbits(lo) | (bfbits(hi) << 16);
}
__device__ __forceinline__ float bf16lo(unsigned int u) {
  return __uint_as_float(u << 16);
}
__device__ __forceinline__ float bf16hi(unsigned int u) {
  return __uint_as_float(u & 0xffff0000u);
}

// Round-1 (known-passing) serial detect.
__global__ void detect_kernel(const void* s, const void* edges, int* flags) {
  if (threadIdx.x == 0) {
    int isf32 = 0;
    const unsigned short* us = (const unsigned short*)s;
    for (int i = 0; i < 1024; i++) {
      unsigned int w = ((unsigned int)us[i]) << 16;
      float f = __uint_as_float(w);
      if (!(fabsf(f) < 1000.f)) { isf32 = 1; break; }
    }
    int isi64 = 1;
    const int* ie = (const int*)edges;
    for (int i = 1; i < 128; i += 2) {
      if (ie[i] != 0) { isi64 = 0; break; }
    }
    flags[0] = isf32;
    flags[1] = isi64;
  }
}

// ---------------------------------------------------------------------------
// CSR build: count -> scan (known-passing wave-shuffle) -> fill
// ---------------------------------------------------------------------------
__global__ void count_kernel(const void* __restrict__ edges, int* __restrict__ cnt,
                             const int* __restrict__ flags, int E) {
  int e = blockIdx.x * blockDim.x + threadIdx.x;
  if (e >= E) return;
  int dst = loadI(edges, (size_t)2 * e, flags[1]);
  atomicAdd(&cnt[dst], 1);
}

__global__ __launch_bounds__(1024) void scan_kernel(const int* __restrict__ cnt,
                                                    int* __restrict__ row_start,
                                                    int* __restrict__ next, int N) {
  __shared__ int woff[16];
  __shared__ int carry_sh;
  const int t = threadIdx.x;
  const int lane = t & 63;
  const int wid = t >> 6;
  if (t == 0) carry_sh = 0;
  __syncthreads();
  for (int base = 0; base < N; base += 1024) {
    int x = (base + t < N) ? cnt[base + t] : 0;
    int incl = x;
    #pragma unroll
    for (int off = 1; off < 64; off <<= 1) {
      int y = __shfl_up(incl, off, 64);
      if (lane >= off) incl += y;
    }
    if (lane == 63) woff[wid] = incl;
    __syncthreads();
    if (wid == 0 && lane < 16) {
      int w = woff[lane];
      int iw = w;
      #pragma unroll
      for (int off = 1; off < 16; off <<= 1) {
        int y = __shfl_up(iw, off, 64);
        if (lane >= off) iw += y;
      }
      woff[lane] = iw - w;
    }
    __syncthreads();
    int carry = carry_sh;
    int excl = carry + woff[wid] + incl - x;
    if (base + t < N) { row_start[base + t] = excl; next[base + t] = excl; }
    __syncthreads();
    if (t == 1023) carry_sh = excl + x;
    __syncthreads();
  }
  if (t == 0) row_start[N] = carry_sh;
}

// fill: scatter edges into CSR order; records:
//   esrc[p]  : src node id
//   efcrn[p] : {fc (PRE=1) or r (PRE=0), rn0, rn1, rn2}
//   erb[p*20..] : 20 values fc*sin((k+1)x)/r  (f32; PRE=1 only)
template <int PRE>
__global__ void fill_kernel(const void* __restrict__ edges,
                            const void* __restrict__ r_ij,
                            const void* __restrict__ rn,
                            int* __restrict__ next,
                            int* __restrict__ esrc,
                            float4* __restrict__ efcrn,
                            float* __restrict__ erb,
                            const int* __restrict__ flags, int E) {
  int e = blockIdx.x * blockDim.x + threadIdx.x;
  if (e >= E) return;
  const int isi64 = flags[1];
  const int isf32 = flags[0];
  const int dst = loadI(edges, (size_t)2 * e, isi64);
  const int src = loadI(edges, (size_t)2 * e + 1, isi64);
  const float r  = loadF(r_ij, e, isf32);
  const float r0 = loadF(rn, (size_t)e * 3 + 0, isf32);
  const float r1 = loadF(rn, (size_t)e * 3 + 1, isf32);
  const float r2 = loadF(rn, (size_t)e * 3 + 2, isf32);
  const int p = atomicAdd(&next[dst], 1);
  esrc[p] = src;
  if (PRE) {
    const float x = (PI_F / RCUT) * r;
    const float s1 = __sinf(x);
    const float c1 = __cosf(x);
    const float fc = 0.5f * (c1 + 1.f);
    efcrn[p] = make_float4(fc, r0, r1, r2);
    const float rf = __builtin_amdgcn_rcpf(r) * fc;
    const float twoc = 2.f * c1;
    float sp = 0.f, sn = s1;
    float rbv[20];
    #pragma unroll
    for (int k = 0; k < 20; k++) {
      rbv[k] = sn * rf;
      const float s2 = twoc * sn - sp;
      sp = sn; sn = s2;
    }
    float4* rb4 = (float4*)(erb + (size_t)p * 20);
    #pragma unroll
    for (int j = 0; j < 5; j++)
      rb4[j] = make_float4(rbv[4 * j], rbv[4 * j + 1], rbv[4 * j + 2], rbv[4 * j + 3]);
  } else {
    efcrn[p] = make_float4(r, r0, r1, r2);
  }
}

// ---------------------------------------------------------------------------
// prep_w: W1 [k][c] -> W1T bf16 [c][k];  W2 [k][c'] -> W2T bf16 [c'][k].
// B-fragments then load as contiguous dwordx4.
// ---------------------------------------------------------------------------
__global__ void prep_w_kernel(const void* __restrict__ W1, const void* __restrict__ W2,
                              unsigned short* __restrict__ W1T,
                              unsigned short* __restrict__ W2T,
                              const int* __restrict__ flags) {
  const int c = blockIdx.x;       // 0..511
  const int k = threadIdx.x;      // 0..127
  const int isf32 = flags[0];
  if (c < CC) {
    W1T[(size_t)c * CC + k] = (unsigned short)bfbits(loadF(W1, (size_t)k * CC + c, isf32));
  } else {
    const int cc = c - CC;
    W2T[(size_t)cc * CC + k] = (unsigned short)bfbits(loadF(W2, (size_t)k * NOUT + cc, isf32));
  }
}

// ---------------------------------------------------------------------------
// MFMA node MLP: 64 nodes/block, 256 threads (4 waves, wave w owns 16 rows).
// A-frag (16x16x32 bf16): lane l -> row = l&15, k = (l>>4)*8 + j  (contiguous)
// B-frag:                 lane l -> col = l&15, k = (l>>4)*8 + j
// D:                      lane l -> col = l&15, row = (l>>4)*4 + reg  [m89]
// LDS: [64][128] bf16, byte-XOR swizzle ^((row&7)<<4) => b128 reads ~2-way.
// ---------------------------------------------------------------------------
template <int ISF32>
__device__ __forceinline__ void mlp_mfma_body(
    const void* __restrict__ s, const void* __restrict__ v,
    const unsigned short* __restrict__ W1T, const unsigned short* __restrict__ W2T,
    const void* __restrict__ b1, const void* __restrict__ b2,
    uint2* __restrict__ tabA, int N) {
  __shared__ unsigned short lds[64 * 128];  // 16 KB
  const int t = threadIdx.x;
  const int l = t & 63;
  const int w = t >> 6;
  const int n0 = blockIdx.x * 64;

  // ---- stage s tile (64x128) as bf16 into swizzled LDS ----
  #pragma unroll
  for (int it = 0; it < 32; ++it) {
    const int id = it * 256 + t;
    const int row = id >> 7;
    const int col = id & 127;
    const int srow = (n0 + row < N) ? (n0 + row) : (N - 1);
    const float f = loadF(s, (size_t)srow * CC + col, ISF32);
    const int byte = (row * 256 + col * 2) ^ ((row & 7) << 4);
    lds[byte >> 1] = (unsigned short)bfbits(f);
  }
  __syncthreads();

  // ---- A-frags (this wave's 16-row stripe), all 4 K-steps ----
  const int arow = w * 16 + (l & 15);
  bf16x8 a[4];
  #pragma unroll
  for (int kk = 0; kk < 4; ++kk) {
    const int byte = (arow * 256 + (kk * 4 + (l >> 4)) * 16) ^ ((arow & 7) << 4);
    a[kk] = *(const bf16x8*)((const char*)lds + byte);
  }

  // ---- layer 1: H = silu(S@W1 + b1), 8 col tiles ----
  f32x4 acc1[8];
  #pragma unroll
  for (int jt = 0; jt < 8; ++jt) { acc1[jt] = f32x4{0.f, 0.f, 0.f, 0.f}; }
  #pragma unroll
  for (int jt = 0; jt < 8; ++jt) {
    const unsigned short* wp = W1T + (size_t)(jt * 16 + (l & 15)) * CC + (l >> 4) * 8;
    #pragma unroll
    for (int kk = 0; kk < 4; ++kk) {
      const bf16x8 b = *(const bf16x8*)(wp + kk * 32);
      acc1[jt] = __builtin_amdgcn_mfma_f32_16x16x32_bf16(a[kk], b, acc1[jt], 0, 0, 0);
    }
  }
  __syncthreads();  // all A-frag reads complete before overwrite

  // ---- bias + silu -> H into same LDS ----
  #pragma unroll
  for (int jt = 0; jt < 8; ++jt) {
    const int c = jt * 16 + (l & 15);
    const float bb = loadF(b1, c, ISF32);
    #pragma unroll
    for (int r = 0; r < 4; ++r) {
      const int row = w * 16 + (l >> 4) * 4 + r;
      const float x = acc1[jt][r] + bb;
      const float h = x / (1.f + __expf(-x));
      const int byte = (row * 256 + c * 2) ^ ((row & 7) << 4);
      lds[byte >> 1] = (unsigned short)bfbits(h);
    }
  }
  __syncthreads();

  // ---- layer 2: OUT = H@W2 + b2, 24 col tiles ----
  bf16x8 a2[4];
  #pragma unroll
  for (int kk = 0; kk < 4; ++kk) {
    const int byte = (arow * 256 + (kk * 4 + (l >> 4)) * 16) ^ ((arow & 7) << 4);
    a2[kk] = *(const bf16x8*)((const char*)lds + byte);
  }
  f32x4 acc2[24];
  #pragma unroll
  for (int jt = 0; jt < 24; ++jt) { acc2[jt] = f32x4{0.f, 0.f, 0.f, 0.f}; }
  #pragma unroll
  for (int jt = 0; jt < 24; ++jt) {
    const unsigned short* wp = W2T + (size_t)(jt * 16 + (l & 15)) * CC + (l >> 4) * 8;
    #pragma unroll
    for (int kk = 0; kk < 4; ++kk) {
      const bf16x8 b = *(const bf16x8*)(wp + kk * 32);
      acc2[jt] = __builtin_amdgcn_mfma_f32_16x16x32_bf16(a2[kk], b, acc2[jt], 0, 0, 0);
    }
  }

  // ---- epilogue: pack tabA = {bf16(sp0)|bf16(sp1), bf16(sp2)|bf16(v0)} ----
  #pragma unroll
  for (int jt = 0; jt < 8; ++jt) {
    const int c = jt * 16 + (l & 15);
    const float bb0 = loadF(b2, c, ISF32);
    const float bb1 = loadF(b2, CC + c, ISF32);
    const float bb2v = loadF(b2, 2 * CC + c, ISF32);
    #pragma unroll
    for (int r = 0; r < 4; ++r) {
      const int n = n0 + w * 16 + (l >> 4) * 4 + r;
      if (n >= N) continue;
      const float v0 = loadF(v, (size_t)n * NOUT + c, ISF32);
      tabA[(size_t)n * CC + c] =
          make_uint2(bfpack(acc2[jt][r] + bb0, acc2[jt + 8][r] + bb1),
                     bfpack(acc2[jt + 16][r] + bb2v, v0));
    }
  }
}

__global__ __launch_bounds__(256, 2) void node_mlp_mfma_kernel(
    const void* __restrict__ s, const void* __restrict__ v,
    const unsigned short* __restrict__ W1T, const unsigned short* __restrict__ W2T,
    const void* __restrict__ b1, const void* __restrict__ b2,
    uint2* __restrict__ tabA, const int* __restrict__ flags, int N) {
  if (flags[0]) mlp_mfma_body<1>(s, v, W1T, W2T, b1, b2, tabA, N);
  else          mlp_mfma_body<0>(s, v, W1T, W2T, b1, b2, tabA, N);
}

// ---------------------------------------------------------------------------
// Self-check: recompute node 0 in scalar f32; flags[2]=1 if tabA matches.
// ---------------------------------------------------------------------------
__global__ void mlp_check_kernel(const void* __restrict__ s,
                                 const void* __restrict__ W1, const void* __restrict__ b1,
                                 const void* __restrict__ W2, const void* __restrict__ b2,
                                 const uint2* __restrict__ tabA, int* __restrict__ flags) {
  __shared__ float h_sh[CC];
  __shared__ int bad;
  const int c = threadIdx.x;
  if (c == 0) bad = 0;
  __syncthreads();
  const int isf32 = flags[0];
  float acc = 0.f;
  for (int k = 0; k < CC; k++)
    acc += loadF(s, k, isf32) * loadF(W1, (size_t)k * CC + c, isf32);
  acc += loadF(b1, c, isf32);
  h_sh[c] = acc / (1.f + __expf(-acc));
  __syncthreads();
  const uint2 ta = tabA[c];
  const float got[3] = {bf16lo(ta.x), bf16hi(ta.x), bf16lo(ta.y)};
  int mybad = 0;
  for (int jj = 0; jj < 3; jj++) {
    float a2 = 0.f;
    for (int k = 0; k < CC; k++)
      a2 += h_sh[k] * loadF(W2, (size_t)k * NOUT + jj * CC + c, isf32);
    a2 += loadF(b2, jj * CC + c, isf32);
    if (fabsf(got[jj] - a2) > 0.25f + 0.02f * fabsf(a2)) mybad = 1;
  }
  if (mybad) atomicOr(&bad, 1);
  __syncthreads();
  if (c == 0) flags[2] = bad ? 0 : 1;
}

// ---------------------------------------------------------------------------
// Fallback scalar node MLP (round-3, known-good). Early-exits if check passed.
// ---------------------------------------------------------------------------
template <int ISF32>
__device__ __forceinline__ void node_mlp_body(
    const void* __restrict__ s, const void* __restrict__ v,
    const void* __restrict__ W1, const void* __restrict__ b1,
    const void* __restrict__ W2, const void* __restrict__ b2,
    uint2* __restrict__ tabA, int N) {
  const int M = 8;
  __shared__ float s_sh[M][CC];
  __shared__ float h_sh[M][CC];
  const int c = threadIdx.x;
  const int n0 = blockIdx.x * M;

  #pragma unroll
  for (int m = 0; m < M; m++) {
    int n = n0 + m;
    s_sh[m][c] = (n < N) ? loadF(s, (size_t)n * CC + c, ISF32) : 0.f;
  }
  __syncthreads();

  float acc[M];
  #pragma unroll
  for (int m = 0; m < M; m++) acc[m] = 0.f;
  for (int k = 0; k < CC; k++) {
    float w = loadF(W1, (size_t)k * CC + c, ISF32);
    #pragma unroll
    for (int m = 0; m < M; m++) acc[m] += s_sh[m][k] * w;
  }
  float bb1 = loadF(b1, c, ISF32);
  #pragma unroll
  for (int m = 0; m < M; m++) {
    float x = acc[m] + bb1;
    h_sh[m][c] = x / (1.f + __expf(-x));
  }
  __syncthreads();

  float a2s[3][M];
  #pragma unroll
  for (int jj = 0; jj < 3; jj++) {
    int j = jj * CC + c;
    float a2[M];
    #pragma unroll
    for (int m = 0; m < M; m++) a2[m] = 0.f;
    for (int k = 0; k < CC; k++) {
      float w = loadF(W2, (size_t)k * NOUT + j, ISF32);
      #pragma unroll
      for (int m = 0; m < M; m++) a2[m] += h_sh[m][k] * w;
    }
    float bb2 = loadF(b2, j, ISF32);
    #pragma unroll
    for (int m = 0; m < M; m++) a2s[jj][m] = a2[m] + bb2;
  }

  #pragma unroll
  for (int m = 0; m < M; m++) {
    int n = n0 + m;
    if (n >= N) continue;
    const float v0 = loadF(v, (size_t)n * NOUT + c, ISF32);
    const size_t tix = (size_t)n * CC + c;
    tabA[tix] = make_uint2(bfpack(a2s[0][m], a2s[1][m]), bfpack(a2s[2][m], v0));
  }
}

__global__ __launch_bounds__(128) void node_mlp_fallback_kernel(
    const void* __restrict__ s, const void* __restrict__ v,
    const void* __restrict__ W1, const void* __restrict__ b1,
    const void* __restrict__ W2, const void* __restrict__ b2,
    uint2* __restrict__ tabA, const int* __restrict__ flags, int N) {
  if (flags[2]) return;  // MFMA result verified OK
  if (flags[0]) node_mlp_body<1>(s, v, W1, b1, W2, b2, tabA, N);
  else          node_mlp_body<0>(s, v, W1, b1, W2, b2, tabA, N);
}

// ---------------------------------------------------------------------------
// Per-node gather-aggregate (round-3, known-good, unchanged).
// ---------------------------------------------------------------------------
template <int ISF32, int PRE>
__device__ __forceinline__ void agg_body(
    const void* __restrict__ s, const void* __restrict__ v,
    const void* __restrict__ Wr, const void* __restrict__ br,
    const uint2* __restrict__ tabA,
    const int* __restrict__ row_start,
    const int* __restrict__ esrc, const float4* __restrict__ efcrn,
    const float* __restrict__ erb,
    void* __restrict__ out, int N) {
  const int n = blockIdx.x;
  const int c = threadIdx.x;

  f32x2 w0p[10], w1p[10], w2p[10];
  #pragma unroll
  for (int j = 0; j < 10; j++) {
    w0p[j] = f32x2{loadF(Wr, (size_t)(2 * j) * NOUT + c, ISF32),
                   loadF(Wr, (size_t)(2 * j + 1) * NOUT + c, ISF32)};
    w1p[j] = f32x2{loadF(Wr, (size_t)(2 * j) * NOUT + CC + c, ISF32),
                   loadF(Wr, (size_t)(2 * j + 1) * NOUT + CC + c, ISF32)};
    w2p[j] = f32x2{loadF(Wr, (size_t)(2 * j) * NOUT + 2 * CC + c, ISF32),
                   loadF(Wr, (size_t)(2 * j + 1) * NOUT + 2 * CC + c, ISF32)};
  }
  const float b0  = loadF(br, c, ISF32);
  const float b1v = loadF(br, CC + c, ISF32);
  const float b2v = loadF(br, 2 * CC + c, ISF32);

  float accs = 0.f, av0 = 0.f, av1 = 0.f, av2 = 0.f;
  const int beg = row_start[n], end = row_start[n + 1];

  int i = beg;
  for (; i + 2 <= end; i += 2) {
    const int srcA = esrc[i];
    const int srcB = esrc[i + 1];
    const float4 frA = efcrn[i];
    const float4 frB = efcrn[i + 1];
    const uint2 taA = tabA[(size_t)srcA * CC + c];
    const uint2 taB = tabA[(size_t)srcB * CC + c];
    const float v1A = loadF(v, (size_t)srcA * NOUT + CC + c, ISF32);
    const float v2A = loadF(v, (size_t)srcA * NOUT + 2 * CC + c, ISF32);
    const float v1B = loadF(v, (size_t)srcB * NOUT + CC + c, ISF32);
    const float v2B = loadF(v, (size_t)srcB * NOUT + 2 * CC + c, ISF32);

    float fcA, fcB;
    f32x2 rbA[10], rbB[10];
    if (PRE) {
      fcA = frA.x;
      fcB = frB.x;
      const f32x2* rpA = (const f32x2*)(erb + (size_t)i * 20);
      const f32x2* rpB = (const f32x2*)(erb + (size_t)(i + 1) * 20);
      #pragma unroll
      for (int j = 0; j < 10; j++) { rbA[j] = rpA[j]; rbB[j] = rpB[j]; }
    } else {
      const float xA = (PI_F / RCUT) * frA.x;
      const float s1A = __sinf(xA), c1A = __cosf(xA);
      fcA = 0.5f * (c1A + 1.f);
      const float rfA = __builtin_amdgcn_rcpf(frA.x) * fcA;
      const float twocA = 2.f * c1A;
      const float xB = (PI_F / RCUT) * frB.x;
      const float s1B = __sinf(xB), c1B = __cosf(xB);
      fcB = 0.5f * (c1B + 1.f);
      const float rfB = __builtin_amdgcn_rcpf(frB.x) * fcB;
      const float twocB = 2.f * c1B;
      float spA = 0.f, snA = s1A, spB = 0.f, snB = s1B;
      #pragma unroll
      for (int j = 0; j < 10; j++) {
        const float qA0 = snA * rfA;
        float s2 = twocA * snA - spA; spA = snA; snA = s2;
        const float qA1 = snA * rfA;
        s2 = twocA * snA - spA; spA = snA; snA = s2;
        rbA[j] = f32x2{qA0, qA1};
        const float qB0 = snB * rfB;
        s2 = twocB * snB - spB; spB = snB; snB = s2;
        const float qB1 = snB * rfB;
        s2 = twocB * snB - spB; spB = snB; snB = s2;
        rbB[j] = f32x2{qB0, qB1};
      }
    }

    f32x2 a0A = f32x2{0.f, 0.f}, a1A = a0A, a2A = a0A;
    f32x2 a0B = a0A, a1B = a0A, a2B = a0A;
    #pragma unroll
    for (int j = 0; j < 10; j++) {
      a0A += rbA[j] * w0p[j];  a0B += rbB[j] * w0p[j];
      a1A += rbA[j] * w1p[j];  a1B += rbB[j] * w1p[j];
      a2A += rbA[j] * w2p[j];  a2B += rbB[j] * w2p[j];
    }

    const float a0Af = fmaf(b0,  fcA, a0A.x + a0A.y);
    const float a1Af = fmaf(b1v, fcA, a1A.x + a1A.y);
    const float a2Af = fmaf(b2v, fcA, a2A.x + a2A.y);
    const float p0A = a0Af * bf16lo(taA.x);
    const float p1A = a1Af * bf16hi(taA.x);
    const float p2A = a2Af * bf16lo(taA.y);
    accs += p1A;
    av0 = fmaf(bf16hi(taA.y), p0A, fmaf(frA.y, p2A, av0));
    av1 = fmaf(v1A, p0A, fmaf(frA.z, p2A, av1));
    av2 = fmaf(v2A, p0A, fmaf(frA.w, p2A, av2));

    const float a0Bf = fmaf(b0,  fcB, a0B.x + a0B.y);
    const float a1Bf = fmaf(b1v, fcB, a1B.x + a1B.y);
    const float a2Bf = fmaf(b2v, fcB, a2B.x + a2B.y);
    const float p0B = a0Bf * bf16lo(taB.x);
    const float p1B = a1Bf * bf16hi(taB.x);
    const float p2B = a2Bf * bf16lo(taB.y);
    accs += p1B;
    av0 = fmaf(bf16hi(taB.y), p0B, fmaf(frB.y, p2B, av0));
    av1 = fmaf(v1B, p0B, fmaf(frB.z, p2B, av1));
    av2 = fmaf(v2B, p0B, fmaf(frB.w, p2B, av2));
  }

  for (; i < end; ++i) {
    const int src = esrc[i];
    const float4 fr = efcrn[i];
    const uint2 ta = tabA[(size_t)src * CC + c];
    const float v1f = loadF(v, (size_t)src * NOUT + CC + c, ISF32);
    const float v2f = loadF(v, (size_t)src * NOUT + 2 * CC + c, ISF32);

    float fc;
    f32x2 rb[10];
    if (PRE) {
      fc = fr.x;
      const f32x2* rp = (const f32x2*)(erb + (size_t)i * 20);
      #pragma unroll
      for (int j = 0; j < 10; j++) rb[j] = rp[j];
    } else {
      const float x = (PI_F / RCUT) * fr.x;
      const float s1 = __sinf(x), c1 = __cosf(x);
      fc = 0.5f * (c1 + 1.f);
      const float rf = __builtin_amdgcn_rcpf(fr.x) * fc;
      const float twoc = 2.f * c1;
      float spv = 0.f, snv = s1;
      #pragma unroll
      for (int j = 0; j < 10; j++) {
        const float q0 = snv * rf;
        float s2 = twoc * snv - spv; spv = snv; snv = s2;
        const float q1 = snv * rf;
        s2 = twoc * snv - spv; spv = snv; snv = s2;
        rb[j] = f32x2{q0, q1};
      }
    }

    f32x2 a0p = f32x2{0.f, 0.f}, a1p = a0p, a2p = a0p;
    #pragma unroll
    for (int j = 0; j < 10; j++) {
      a0p += rb[j] * w0p[j];
      a1p += rb[j] * w1p[j];
      a2p += rb[j] * w2p[j];
    }

    const float a0 = fmaf(b0,  fc, a0p.x + a0p.y);
    const float a1 = fmaf(b1v, fc, a1p.x + a1p.y);
    const float a2 = fmaf(b2v, fc, a2p.x + a2p.y);
    const float p0 = a0 * bf16lo(ta.x);
    const float p1 = a1 * bf16hi(ta.x);
    const float p2 = a2 * bf16lo(ta.y);
    accs += p1;
    av0 = fmaf(bf16hi(ta.y), p0, fmaf(fr.y, p2, av0));
    av1 = fmaf(v1f, p0, fmaf(fr.z, p2, av1));
    av2 = fmaf(v2f, p0, fmaf(fr.w, p2, av2));
  }

  const size_t si = (size_t)n * CC + c;
  const size_t vi = (size_t)n * NOUT;
  const float so = loadF(s, si, ISF32) + accs;
  const float o0 = loadF(v, vi + 0 * CC + c, ISF32) + av0;
  const float o1 = loadF(v, vi + 1 * CC + c, ISF32) + av1;
  const float o2 = loadF(v, vi + 2 * CC + c, ISF32) + av2;
  const size_t vo = (size_t)N * CC + vi;
  if (ISF32) {
    float* o = (float*)out;
    o[si] = so;
    o[vo + 0 * CC + c] = o0;
    o[vo + 1 * CC + c] = o1;
    o[vo + 2 * CC + c] = o2;
  } else {
    __hip_bfloat16* o = (__hip_bfloat16*)out;
    o[si] = __float2bfloat16(so);
    o[vo + 0 * CC + c] = __float2bfloat16(o0);
    o[vo + 1 * CC + c] = __float2bfloat16(o1);
    o[vo + 2 * CC + c] = __float2bfloat16(o2);
  }
}

template <int PRE>
__global__ __launch_bounds__(128, 3) void aggregate_kernel(
    const void* __restrict__ s, const void* __restrict__ v,
    const void* __restrict__ Wr, const void* __restrict__ br,
    const uint2* __restrict__ tabA,
    const int* __restrict__ row_start,
    const int* __restrict__ esrc, const float4* __restrict__ efcrn,
    const float* __restrict__ erb,
    void* __restrict__ out, const int* __restrict__ flags, int N) {
  if (flags[0]) agg_body<1, PRE>(s, v, Wr, br, tabA, row_start, esrc, efcrn, erb, out, N);
  else          agg_body<0, PRE>(s, v, Wr, br, tabA, row_start, esrc, efcrn, erb, out, N);
}

extern "C" void kernel_launch(void* const* d_in, const int* in_sizes, int n_in,
                              void* d_out, int out_size, void* d_ws, size_t ws_size,
                              hipStream_t stream) {
  const void* s     = d_in[0];
  const void* v     = d_in[1];
  const void* edges = d_in[2];
  const void* r_ij  = d_in[3];
  const void* rn    = d_in[4];
  const void* W1    = d_in[5];
  const void* b1    = d_in[6];
  const void* W2    = d_in[7];
  const void* b2    = d_in[8];
  const void* Wr    = d_in[9];
  const void* br    = d_in[10];

  const int N = in_sizes[0] / CC;     // 50000
  const int E = in_sizes[3];          // 400000

  // ws: flags | W1T | W2T | tabA | efcrn | esrc | cnt | row_start | next | erb
  char* ws = (char*)d_ws;
  int* flags = (int*)ws;
  size_t off = 256;
  auto align16 = [](size_t x) { return (x + 15) & ~(size_t)15; };
  unsigned short* W1T = (unsigned short*)(ws + off);  off += align16((size_t)CC * CC * 2);
  unsigned short* W2T = (unsigned short*)(ws + off);  off += align16((size_t)NOUT * CC * 2);
  uint2* tabA = (uint2*)(ws + off);      off += align16((size_t)N * CC * 8);
  float4* efcrn = (float4*)(ws + off);   off += align16((size_t)E * 16);
  int* esrc = (int*)(ws + off);          off += align16((size_t)E * 4);
  int* cnt = (int*)(ws + off);           off += align16((size_t)N * 4);
  int* row_start = (int*)(ws + off);     off += align16((size_t)(N + 1) * 4);
  int* next = (int*)(ws + off);          off += align16((size_t)N * 4);
  float* erb = (float*)(ws + off);
  const size_t off_erb_end = off + (size_t)E * 20 * 4;
  const int pre = (ws_size >= off_erb_end) ? 1 : 0;

  hipMemsetAsync(cnt, 0, (size_t)N * sizeof(int), stream);

  detect_kernel<<<1, 64, 0, stream>>>(s, edges, flags);
  count_kernel<<<(E + 255) / 256, 256, 0, stream>>>(edges, cnt, flags, E);
  scan_kernel<<<1, 1024, 0, stream>>>(cnt, row_start, next, N);
  if (pre)
    fill_kernel<1><<<(E + 255) / 256, 256, 0, stream>>>(edges, r_ij, rn, next,
                                                        esrc, efcrn, erb, flags, E);
  else
    fill_kernel<0><<<(E + 255) / 256, 256, 0, stream>>>(edges, r_ij, rn, next,
                                                        esrc, efcrn, erb, flags, E);
  prep_w_kernel<<<CC + NOUT, 128, 0, stream>>>(W1, W2, W1T, W2T, flags);
  node_mlp_mfma_kernel<<<(N + 63) / 64, 256, 0, stream>>>(s, v, W1T, W2T, b1, b2,
                                                          tabA, flags, N);
  mlp_check_kernel<<<1, 128, 0, stream>>>(s, W1, b1, W2, b2, tabA, flags);
  node_mlp_fallback_kernel<<<(N + 7) / 8, 128, 0, stream>>>(s, v, W1, b1, W2, b2,
                                                            tabA, flags, N);
  if (pre)
    aggregate_kernel<1><<<N, 128, 0, stream>>>(s, v, Wr, br, tabA, row_start,
                                               esrc, efcrn, erb, d_out, flags, N);
  else
    aggregate_kernel<0><<<N, 128, 0, stream>>>(s, v, Wr, br, tabA, row_start,
                                               esrc, efcrn, erb, d_out, flags, N);
}

// Round 5
// 567.558 us; speedup vs baseline: 1.5257x; 1.0779x over previous
//
#include <hip/hip_runtime.h>
#include <hip/hip_bf16.h>

#define CC 128
#define NOUT 384
#define PI_F 3.14159265358979323846f
#define RCUT 5.0f

typedef float f32x2 __attribute__((ext_vector_type(2)));
typedef __attribute__((ext_vector_type(8))) short bf16x8;
typedef __attribute__((ext_vector_type(4))) float f32x4;

// ---------------------------------------------------------------------------
// Dtype-agnostic loads (flags discovered on device; graph-safe).
// ---------------------------------------------------------------------------
__device__ __forceinline__ float loadF(const void* p, size_t i, int isf32) {
  if (isf32) return ((const float*)p)[i];
  unsigned int w = ((unsigned int)((const unsigned short*)p)[i]) << 16;
  return __uint_as_float(w);
}
__device__ __forceinline__ int loadI(const void* p, size_t i, int isi64) {
  if (isi64) return (int)((const long long*)p)[i];
  return ((const int*)p)[i];
}
__device__ __forceinline__ unsigned int bfbits(float f) {
  __hip_bfloat16 h = __float2bfloat16(f);
  unsigned short u;
  __builtin_memcpy(&u, &h, 2);
  return (unsigned int)u;
}
__device__ __forceinline__ unsigned int bfpack(float lo, float hi) {
  return bfbits(lo) | (bfbits(hi) << 16);
}
__device__ __forceinline__ float bf16lo(unsigned int u) {
  return __uint_as_float(u << 16);
}
__device__ __forceinline__ float bf16hi(unsigned int u) {
  return __uint_as_float(u & 0xffff0000u);
}

// Round-1 (known-passing) serial detect.
__global__ void detect_kernel(const void* s, const void* edges, int* flags) {
  if (threadIdx.x == 0) {
    int isf32 = 0;
    const unsigned short* us = (const unsigned short*)s;
    for (int i = 0; i < 1024; i++) {
      unsigned int w = ((unsigned int)us[i]) << 16;
      float f = __uint_as_float(w);
      if (!(fabsf(f) < 1000.f)) { isf32 = 1; break; }
    }
    int isi64 = 1;
    const int* ie = (const int*)edges;
    for (int i = 1; i < 128; i += 2) {
      if (ie[i] != 0) { isi64 = 0; break; }
    }
    flags[0] = isf32;
    flags[1] = isi64;
  }
}

// ---------------------------------------------------------------------------
// CSR build: count -> scan -> fill
// ---------------------------------------------------------------------------
__global__ void count_kernel(const void* __restrict__ edges, int* __restrict__ cnt,
                             const int* __restrict__ flags, int E) {
  int e = blockIdx.x * blockDim.x + threadIdx.x;
  if (e >= E) return;
  int dst = loadI(edges, (size_t)2 * e, flags[1]);
  atomicAdd(&cnt[dst], 1);
}

// Multi-block scan: part1 (local exclusive scan, 4096/block) ->
// part2 (scan of <=64 block sums) -> part3 (apply block offsets).
__global__ __launch_bounds__(1024) void scan_part1(const int* __restrict__ cnt,
                                                   int* __restrict__ row_start,
                                                   int* __restrict__ bsum, int N) {
  __shared__ int woff[16];
  const int t = threadIdx.x;
  const int lane = t & 63;
  const int wid = t >> 6;
  const int idx = blockIdx.x * 4096 + t * 4;
  int4 x = make_int4(0, 0, 0, 0);
  if (idx < N) x = *(const int4*)(cnt + idx);   // N % 4 == 0
  const int ssum = x.x + x.y + x.z + x.w;
  int incl = ssum;
  #pragma unroll
  for (int off = 1; off < 64; off <<= 1) {
    int y = __shfl_up(incl, off, 64);
    if (lane >= off) incl += y;
  }
  if (lane == 63) woff[wid] = incl;
  __syncthreads();
  if (wid == 0 && lane < 16) {
    int w = woff[lane];
    int iw = w;
    #pragma unroll
    for (int off = 1; off < 16; off <<= 1) {
      int y = __shfl_up(iw, off, 64);
      if (lane >= off) iw += y;
    }
    woff[lane] = iw - w;   // exclusive wave offsets
  }
  __syncthreads();
  const int ebase = woff[wid] + (incl - ssum);
  if (idx < N) {
    int4 r;
    r.x = ebase;
    r.y = ebase + x.x;
    r.z = r.y + x.y;
    r.w = r.z + x.z;
    *(int4*)(row_start + idx) = r;
  }
  if (t == 1023) bsum[blockIdx.x] = woff[15] + incl;  // block total
}

__global__ void scan_part2(const int* __restrict__ bsum, int* __restrict__ boff,
                           int* __restrict__ row_start, int NB, int N) {
  const int lane = threadIdx.x;  // 64 threads, NB <= 64
  int v = (lane < NB) ? bsum[lane] : 0;
  int incl = v;
  #pragma unroll
  for (int off = 1; off < 64; off <<= 1) {
    int y = __shfl_up(incl, off, 64);
    if (lane >= off) incl += y;
  }
  if (lane < NB) boff[lane] = incl - v;   // exclusive
  if (lane == NB - 1) row_start[N] = incl; // grand total = E
}

__global__ __launch_bounds__(1024) void scan_part3(int* __restrict__ row_start,
                                                   int* __restrict__ next,
                                                   const int* __restrict__ boff, int N) {
  const int idx = blockIdx.x * 4096 + threadIdx.x * 4;
  if (idx >= N) return;
  const int b = boff[blockIdx.x];
  int4 r = *(const int4*)(row_start + idx);
  r.x += b; r.y += b; r.z += b; r.w += b;
  *(int4*)(row_start + idx) = r;
  *(int4*)(next + idx) = r;
}

// Fallback single-block scan (only if NB > 64; never for N=50000).
__global__ __launch_bounds__(1024) void scan_kernel(const int* __restrict__ cnt,
                                                    int* __restrict__ row_start,
                                                    int* __restrict__ next, int N) {
  __shared__ int woff[16];
  __shared__ int carry_sh;
  const int t = threadIdx.x;
  const int lane = t & 63;
  const int wid = t >> 6;
  if (t == 0) carry_sh = 0;
  __syncthreads();
  for (int base = 0; base < N; base += 1024) {
    int x = (base + t < N) ? cnt[base + t] : 0;
    int incl = x;
    #pragma unroll
    for (int off = 1; off < 64; off <<= 1) {
      int y = __shfl_up(incl, off, 64);
      if (lane >= off) incl += y;
    }
    if (lane == 63) woff[wid] = incl;
    __syncthreads();
    if (wid == 0 && lane < 16) {
      int w = woff[lane];
      int iw = w;
      #pragma unroll
      for (int off = 1; off < 16; off <<= 1) {
        int y = __shfl_up(iw, off, 64);
        if (lane >= off) iw += y;
      }
      woff[lane] = iw - w;
    }
    __syncthreads();
    int carry = carry_sh;
    int excl = carry + woff[wid] + incl - x;
    if (base + t < N) { row_start[base + t] = excl; next[base + t] = excl; }
    __syncthreads();
    if (t == 1023) carry_sh = excl + x;
    __syncthreads();
  }
  if (t == 0) row_start[N] = carry_sh;
}

// fill: scatter edges into CSR order; records:
//   esrc[p]  : src node id
//   efcrn[p] : {fc (PRE=1) or r (PRE=0), rn0, rn1, rn2}
//   erb[p*20..] : 20 values fc*sin((k+1)x)/r  (f32; PRE=1 only)
template <int PRE>
__global__ void fill_kernel(const void* __restrict__ edges,
                            const void* __restrict__ r_ij,
                            const void* __restrict__ rn,
                            int* __restrict__ next,
                            int* __restrict__ esrc,
                            float4* __restrict__ efcrn,
                            float* __restrict__ erb,
                            const int* __restrict__ flags, int E) {
  int e = blockIdx.x * blockDim.x + threadIdx.x;
  if (e >= E) return;
  const int isi64 = flags[1];
  const int isf32 = flags[0];
  const int dst = loadI(edges, (size_t)2 * e, isi64);
  const int src = loadI(edges, (size_t)2 * e + 1, isi64);
  const float r  = loadF(r_ij, e, isf32);
  const float r0 = loadF(rn, (size_t)e * 3 + 0, isf32);
  const float r1 = loadF(rn, (size_t)e * 3 + 1, isf32);
  const float r2 = loadF(rn, (size_t)e * 3 + 2, isf32);
  const int p = atomicAdd(&next[dst], 1);
  esrc[p] = src;
  if (PRE) {
    const float x = (PI_F / RCUT) * r;
    const float s1 = __sinf(x);
    const float c1 = __cosf(x);
    const float fc = 0.5f * (c1 + 1.f);
    efcrn[p] = make_float4(fc, r0, r1, r2);
    const float rf = __builtin_amdgcn_rcpf(r) * fc;
    const float twoc = 2.f * c1;
    float sp = 0.f, sn = s1;
    float rbv[20];
    #pragma unroll
    for (int k = 0; k < 20; k++) {
      rbv[k] = sn * rf;
      const float s2 = twoc * sn - sp;
      sp = sn; sn = s2;
    }
    float4* rb4 = (float4*)(erb + (size_t)p * 20);
    #pragma unroll
    for (int j = 0; j < 5; j++)
      rb4[j] = make_float4(rbv[4 * j], rbv[4 * j + 1], rbv[4 * j + 2], rbv[4 * j + 3]);
  } else {
    efcrn[p] = make_float4(r, r0, r1, r2);
  }
}

// ---------------------------------------------------------------------------
// prep_w: W1 [k][c] -> W1T bf16 [c][k];  W2 [k][c'] -> W2T bf16 [c'][k].
// ---------------------------------------------------------------------------
__global__ void prep_w_kernel(const void* __restrict__ W1, const void* __restrict__ W2,
                              unsigned short* __restrict__ W1T,
                              unsigned short* __restrict__ W2T,
                              const int* __restrict__ flags) {
  const int c = blockIdx.x;       // 0..511
  const int k = threadIdx.x;      // 0..127
  const int isf32 = flags[0];
  if (c < CC) {
    W1T[(size_t)c * CC + k] = (unsigned short)bfbits(loadF(W1, (size_t)k * CC + c, isf32));
  } else {
    const int cc = c - CC;
    W2T[(size_t)cc * CC + k] = (unsigned short)bfbits(loadF(W2, (size_t)k * NOUT + cc, isf32));
  }
}

// ---------------------------------------------------------------------------
// MFMA node MLP (HW-verified round 4): 64 nodes/block, 256 threads / 4 waves.
// A-frag (16x16x32 bf16): lane l -> row = l&15, k = (l>>4)*8 + j
// B-frag:                 lane l -> col = l&15, k = (l>>4)*8 + j
// D:                      lane l -> col = l&15, row = (l>>4)*4 + reg  [m89]
// Epilogue additionally packs tabB = bf16(v1)|bf16(v2) (coalesced v reads).
// ---------------------------------------------------------------------------
template <int ISF32>
__device__ __forceinline__ void mlp_mfma_body(
    const void* __restrict__ s, const void* __restrict__ v,
    const unsigned short* __restrict__ W1T, const unsigned short* __restrict__ W2T,
    const void* __restrict__ b1, const void* __restrict__ b2,
    uint2* __restrict__ tabA, unsigned int* __restrict__ tabB, int tb, int N) {
  __shared__ unsigned short lds[64 * 128];  // 16 KB
  const int t = threadIdx.x;
  const int l = t & 63;
  const int w = t >> 6;
  const int n0 = blockIdx.x * 64;

  // ---- stage s tile (64x128) as bf16 into swizzled LDS ----
  #pragma unroll
  for (int it = 0; it < 32; ++it) {
    const int id = it * 256 + t;
    const int row = id >> 7;
    const int col = id & 127;
    const int srow = (n0 + row < N) ? (n0 + row) : (N - 1);
    const float f = loadF(s, (size_t)srow * CC + col, ISF32);
    const int byte = (row * 256 + col * 2) ^ ((row & 7) << 4);
    lds[byte >> 1] = (unsigned short)bfbits(f);
  }
  __syncthreads();

  // ---- A-frags (this wave's 16-row stripe), all 4 K-steps ----
  const int arow = w * 16 + (l & 15);
  bf16x8 a[4];
  #pragma unroll
  for (int kk = 0; kk < 4; ++kk) {
    const int byte = (arow * 256 + (kk * 4 + (l >> 4)) * 16) ^ ((arow & 7) << 4);
    a[kk] = *(const bf16x8*)((const char*)lds + byte);
  }

  // ---- layer 1: H = silu(S@W1 + b1), 8 col tiles ----
  f32x4 acc1[8];
  #pragma unroll
  for (int jt = 0; jt < 8; ++jt) { acc1[jt] = f32x4{0.f, 0.f, 0.f, 0.f}; }
  #pragma unroll
  for (int jt = 0; jt < 8; ++jt) {
    const unsigned short* wp = W1T + (size_t)(jt * 16 + (l & 15)) * CC + (l >> 4) * 8;
    #pragma unroll
    for (int kk = 0; kk < 4; ++kk) {
      const bf16x8 b = *(const bf16x8*)(wp + kk * 32);
      acc1[jt] = __builtin_amdgcn_mfma_f32_16x16x32_bf16(a[kk], b, acc1[jt], 0, 0, 0);
    }
  }
  __syncthreads();  // all A-frag reads complete before overwrite

  // ---- bias + silu -> H into same LDS ----
  #pragma unroll
  for (int jt = 0; jt < 8; ++jt) {
    const int c = jt * 16 + (l & 15);
    const float bb = loadF(b1, c, ISF32);
    #pragma unroll
    for (int r = 0; r < 4; ++r) {
      const int row = w * 16 + (l >> 4) * 4 + r;
      const float x = acc1[jt][r] + bb;
      const float h = x / (1.f + __expf(-x));
      const int byte = (row * 256 + c * 2) ^ ((row & 7) << 4);
      lds[byte >> 1] = (unsigned short)bfbits(h);
    }
  }
  __syncthreads();

  // ---- layer 2: OUT = H@W2 + b2, 24 col tiles ----
  bf16x8 a2[4];
  #pragma unroll
  for (int kk = 0; kk < 4; ++kk) {
    const int byte = (arow * 256 + (kk * 4 + (l >> 4)) * 16) ^ ((arow & 7) << 4);
    a2[kk] = *(const bf16x8*)((const char*)lds + byte);
  }
  f32x4 acc2[24];
  #pragma unroll
  for (int jt = 0; jt < 24; ++jt) { acc2[jt] = f32x4{0.f, 0.f, 0.f, 0.f}; }
  #pragma unroll
  for (int jt = 0; jt < 24; ++jt) {
    const unsigned short* wp = W2T + (size_t)(jt * 16 + (l & 15)) * CC + (l >> 4) * 8;
    #pragma unroll
    for (int kk = 0; kk < 4; ++kk) {
      const bf16x8 b = *(const bf16x8*)(wp + kk * 32);
      acc2[jt] = __builtin_amdgcn_mfma_f32_16x16x32_bf16(a2[kk], b, acc2[jt], 0, 0, 0);
    }
  }

  // ---- epilogue: tabA = {sp0|sp1, sp2|v0};  tabB = {v1|v2} (if tb) ----
  #pragma unroll
  for (int jt = 0; jt < 8; ++jt) {
    const int c = jt * 16 + (l & 15);
    const float bb0 = loadF(b2, c, ISF32);
    const float bb1 = loadF(b2, CC + c, ISF32);
    const float bb2v = loadF(b2, 2 * CC + c, ISF32);
    #pragma unroll
    for (int r = 0; r < 4; ++r) {
      const int n = n0 + w * 16 + (l >> 4) * 4 + r;
      if (n >= N) continue;
      const size_t vb = (size_t)n * NOUT + c;
      const float v0 = loadF(v, vb, ISF32);
      tabA[(size_t)n * CC + c] =
          make_uint2(bfpack(acc2[jt][r] + bb0, acc2[jt + 8][r] + bb1),
                     bfpack(acc2[jt + 16][r] + bb2v, v0));
      if (tb) {
        const float v1 = loadF(v, vb + CC, ISF32);
        const float v2 = loadF(v, vb + 2 * CC, ISF32);
        tabB[(size_t)n * CC + c] = bfpack(v1, v2);
      }
    }
  }
}

__global__ __launch_bounds__(256, 2) void node_mlp_mfma_kernel(
    const void* __restrict__ s, const void* __restrict__ v,
    const unsigned short* __restrict__ W1T, const unsigned short* __restrict__ W2T,
    const void* __restrict__ b1, const void* __restrict__ b2,
    uint2* __restrict__ tabA, unsigned int* __restrict__ tabB, int tb,
    const int* __restrict__ flags, int N) {
  if (flags[0]) mlp_mfma_body<1>(s, v, W1T, W2T, b1, b2, tabA, tabB, tb, N);
  else          mlp_mfma_body<0>(s, v, W1T, W2T, b1, b2, tabA, tabB, tb, N);
}

// ---------------------------------------------------------------------------
// Per-node gather-aggregate (round-3 structure; TB adds packed v1|v2 gather).
// ---------------------------------------------------------------------------
template <int ISF32, int PRE, int TB>
__device__ __forceinline__ void agg_body(
    const void* __restrict__ s, const void* __restrict__ v,
    const void* __restrict__ Wr, const void* __restrict__ br,
    const uint2* __restrict__ tabA, const unsigned int* __restrict__ tabB,
    const int* __restrict__ row_start,
    const int* __restrict__ esrc, const float4* __restrict__ efcrn,
    const float* __restrict__ erb,
    void* __restrict__ out, int N) {
  const int n = blockIdx.x;
  const int c = threadIdx.x;

  f32x2 w0p[10], w1p[10], w2p[10];
  #pragma unroll
  for (int j = 0; j < 10; j++) {
    w0p[j] = f32x2{loadF(Wr, (size_t)(2 * j) * NOUT + c, ISF32),
                   loadF(Wr, (size_t)(2 * j + 1) * NOUT + c, ISF32)};
    w1p[j] = f32x2{loadF(Wr, (size_t)(2 * j) * NOUT + CC + c, ISF32),
                   loadF(Wr, (size_t)(2 * j + 1) * NOUT + CC + c, ISF32)};
    w2p[j] = f32x2{loadF(Wr, (size_t)(2 * j) * NOUT + 2 * CC + c, ISF32),
                   loadF(Wr, (size_t)(2 * j + 1) * NOUT + 2 * CC + c, ISF32)};
  }
  const float b0  = loadF(br, c, ISF32);
  const float b1v = loadF(br, CC + c, ISF32);
  const float b2v = loadF(br, 2 * CC + c, ISF32);

  float accs = 0.f, av0 = 0.f, av1 = 0.f, av2 = 0.f;
  const int beg = row_start[n], end = row_start[n + 1];

  int i = beg;
  for (; i + 2 <= end; i += 2) {
    const int srcA = esrc[i];
    const int srcB = esrc[i + 1];
    const float4 frA = efcrn[i];
    const float4 frB = efcrn[i + 1];
    const uint2 taA = tabA[(size_t)srcA * CC + c];
    const uint2 taB = tabA[(size_t)srcB * CC + c];
    float v1A, v2A, v1B, v2B;
    if (TB) {
      const unsigned int tA = tabB[(size_t)srcA * CC + c];
      const unsigned int tB = tabB[(size_t)srcB * CC + c];
      v1A = bf16lo(tA); v2A = bf16hi(tA);
      v1B = bf16lo(tB); v2B = bf16hi(tB);
    } else {
      v1A = loadF(v, (size_t)srcA * NOUT + CC + c, ISF32);
      v2A = loadF(v, (size_t)srcA * NOUT + 2 * CC + c, ISF32);
      v1B = loadF(v, (size_t)srcB * NOUT + CC + c, ISF32);
      v2B = loadF(v, (size_t)srcB * NOUT + 2 * CC + c, ISF32);
    }

    float fcA, fcB;
    f32x2 rbA[10], rbB[10];
    if (PRE) {
      fcA = frA.x;
      fcB = frB.x;
      const f32x2* rpA = (const f32x2*)(erb + (size_t)i * 20);
      const f32x2* rpB = (const f32x2*)(erb + (size_t)(i + 1) * 20);
      #pragma unroll
      for (int j = 0; j < 10; j++) { rbA[j] = rpA[j]; rbB[j] = rpB[j]; }
    } else {
      const float xA = (PI_F / RCUT) * frA.x;
      const float s1A = __sinf(xA), c1A = __cosf(xA);
      fcA = 0.5f * (c1A + 1.f);
      const float rfA = __builtin_amdgcn_rcpf(frA.x) * fcA;
      const float twocA = 2.f * c1A;
      const float xB = (PI_F / RCUT) * frB.x;
      const float s1B = __sinf(xB), c1B = __cosf(xB);
      fcB = 0.5f * (c1B + 1.f);
      const float rfB = __builtin_amdgcn_rcpf(frB.x) * fcB;
      const float twocB = 2.f * c1B;
      float spA = 0.f, snA = s1A, spB = 0.f, snB = s1B;
      #pragma unroll
      for (int j = 0; j < 10; j++) {
        const float qA0 = snA * rfA;
        float s2 = twocA * snA - spA; spA = snA; snA = s2;
        const float qA1 = snA * rfA;
        s2 = twocA * snA - spA; spA = snA; snA = s2;
        rbA[j] = f32x2{qA0, qA1};
        const float qB0 = snB * rfB;
        s2 = twocB * snB - spB; spB = snB; snB = s2;
        const float qB1 = snB * rfB;
        s2 = twocB * snB - spB; spB = snB; snB = s2;
        rbB[j] = f32x2{qB0, qB1};
      }
    }

    f32x2 a0A = f32x2{0.f, 0.f}, a1A = a0A, a2A = a0A;
    f32x2 a0B = a0A, a1B = a0A, a2B = a0A;
    #pragma unroll
    for (int j = 0; j < 10; j++) {
      a0A += rbA[j] * w0p[j];  a0B += rbB[j] * w0p[j];
      a1A += rbA[j] * w1p[j];  a1B += rbB[j] * w1p[j];
      a2A += rbA[j] * w2p[j];  a2B += rbB[j] * w2p[j];
    }

    const float a0Af = fmaf(b0,  fcA, a0A.x + a0A.y);
    const float a1Af = fmaf(b1v, fcA, a1A.x + a1A.y);
    const float a2Af = fmaf(b2v, fcA, a2A.x + a2A.y);
    const float p0A = a0Af * bf16lo(taA.x);
    const float p1A = a1Af * bf16hi(taA.x);
    const float p2A = a2Af * bf16lo(taA.y);
    accs += p1A;
    av0 = fmaf(bf16hi(taA.y), p0A, fmaf(frA.y, p2A, av0));
    av1 = fmaf(v1A, p0A, fmaf(frA.z, p2A, av1));
    av2 = fmaf(v2A, p0A, fmaf(frA.w, p2A, av2));

    const float a0Bf = fmaf(b0,  fcB, a0B.x + a0B.y);
    const float a1Bf = fmaf(b1v, fcB, a1B.x + a1B.y);
    const float a2Bf = fmaf(b2v, fcB, a2B.x + a2B.y);
    const float p0B = a0Bf * bf16lo(taB.x);
    const float p1B = a1Bf * bf16hi(taB.x);
    const float p2B = a2Bf * bf16lo(taB.y);
    accs += p1B;
    av0 = fmaf(bf16hi(taB.y), p0B, fmaf(frB.y, p2B, av0));
    av1 = fmaf(v1B, p0B, fmaf(frB.z, p2B, av1));
    av2 = fmaf(v2B, p0B, fmaf(frB.w, p2B, av2));
  }

  for (; i < end; ++i) {
    const int src = esrc[i];
    const float4 fr = efcrn[i];
    const uint2 ta = tabA[(size_t)src * CC + c];
    float v1f, v2f;
    if (TB) {
      const unsigned int tB = tabB[(size_t)src * CC + c];
      v1f = bf16lo(tB); v2f = bf16hi(tB);
    } else {
      v1f = loadF(v, (size_t)src * NOUT + CC + c, ISF32);
      v2f = loadF(v, (size_t)src * NOUT + 2 * CC + c, ISF32);
    }

    float fc;
    f32x2 rb[10];
    if (PRE) {
      fc = fr.x;
      const f32x2* rp = (const f32x2*)(erb + (size_t)i * 20);
      #pragma unroll
      for (int j = 0; j < 10; j++) rb[j] = rp[j];
    } else {
      const float x = (PI_F / RCUT) * fr.x;
      const float s1 = __sinf(x), c1 = __cosf(x);
      fc = 0.5f * (c1 + 1.f);
      const float rf = __builtin_amdgcn_rcpf(fr.x) * fc;
      const float twoc = 2.f * c1;
      float spv = 0.f, snv = s1;
      #pragma unroll
      for (int j = 0; j < 10; j++) {
        const float q0 = snv * rf;
        float s2 = twoc * snv - spv; spv = snv; snv = s2;
        const float q1 = snv * rf;
        s2 = twoc * snv - spv; spv = snv; snv = s2;
        rb[j] = f32x2{q0, q1};
      }
    }

    f32x2 a0p = f32x2{0.f, 0.f}, a1p = a0p, a2p = a0p;
    #pragma unroll
    for (int j = 0; j < 10; j++) {
      a0p += rb[j] * w0p[j];
      a1p += rb[j] * w1p[j];
      a2p += rb[j] * w2p[j];
    }

    const float a0 = fmaf(b0,  fc, a0p.x + a0p.y);
    const float a1 = fmaf(b1v, fc, a1p.x + a1p.y);
    const float a2 = fmaf(b2v, fc, a2p.x + a2p.y);
    const float p0 = a0 * bf16lo(ta.x);
    const float p1 = a1 * bf16hi(ta.x);
    const float p2 = a2 * bf16lo(ta.y);
    accs += p1;
    av0 = fmaf(bf16hi(ta.y), p0, fmaf(fr.y, p2, av0));
    av1 = fmaf(v1f, p0, fmaf(fr.z, p2, av1));
    av2 = fmaf(v2f, p0, fmaf(fr.w, p2, av2));
  }

  const size_t si = (size_t)n * CC + c;
  const size_t vi = (size_t)n * NOUT;
  const float so = loadF(s, si, ISF32) + accs;
  const float o0 = loadF(v, vi + 0 * CC + c, ISF32) + av0;
  const float o1 = loadF(v, vi + 1 * CC + c, ISF32) + av1;
  const float o2 = loadF(v, vi + 2 * CC + c, ISF32) + av2;
  const size_t vo = (size_t)N * CC + vi;
  if (ISF32) {
    float* o = (float*)out;
    o[si] = so;
    o[vo + 0 * CC + c] = o0;
    o[vo + 1 * CC + c] = o1;
    o[vo + 2 * CC + c] = o2;
  } else {
    __hip_bfloat16* o = (__hip_bfloat16*)out;
    o[si] = __float2bfloat16(so);
    o[vo + 0 * CC + c] = __float2bfloat16(o0);
    o[vo + 1 * CC + c] = __float2bfloat16(o1);
    o[vo + 2 * CC + c] = __float2bfloat16(o2);
  }
}

template <int PRE, int TB>
__global__ __launch_bounds__(128, 3) void aggregate_kernel(
    const void* __restrict__ s, const void* __restrict__ v,
    const void* __restrict__ Wr, const void* __restrict__ br,
    const uint2* __restrict__ tabA, const unsigned int* __restrict__ tabB,
    const int* __restrict__ row_start,
    const int* __restrict__ esrc, const float4* __restrict__ efcrn,
    const float* __restrict__ erb,
    void* __restrict__ out, const int* __restrict__ flags, int N) {
  if (flags[0]) agg_body<1, PRE, TB>(s, v, Wr, br, tabA, tabB, row_start, esrc, efcrn, erb, out, N);
  else          agg_body<0, PRE, TB>(s, v, Wr, br, tabA, tabB, row_start, esrc, efcrn, erb, out, N);
}

extern "C" void kernel_launch(void* const* d_in, const int* in_sizes, int n_in,
                              void* d_out, int out_size, void* d_ws, size_t ws_size,
                              hipStream_t stream) {
  const void* s     = d_in[0];
  const void* v     = d_in[1];
  const void* edges = d_in[2];
  const void* r_ij  = d_in[3];
  const void* rn    = d_in[4];
  const void* W1    = d_in[5];
  const void* b1    = d_in[6];
  const void* W2    = d_in[7];
  const void* b2    = d_in[8];
  const void* Wr    = d_in[9];
  const void* br    = d_in[10];

  const int N = in_sizes[0] / CC;     // 50000
  const int E = in_sizes[3];          // 400000

  // ws: flags(256) | bsum(256) | boff(256) | W1T | W2T | tabA | efcrn | esrc
  //     | cnt | row_start | next | erb | tabB
  char* ws = (char*)d_ws;
  int* flags = (int*)ws;
  int* bsum = (int*)(ws + 256);
  int* boff = (int*)(ws + 512);
  size_t off = 768;
  auto align16 = [](size_t x) { return (x + 15) & ~(size_t)15; };
  unsigned short* W1T = (unsigned short*)(ws + off);  off += align16((size_t)CC * CC * 2);
  unsigned short* W2T = (unsigned short*)(ws + off);  off += align16((size_t)NOUT * CC * 2);
  uint2* tabA = (uint2*)(ws + off);      off += align16((size_t)N * CC * 8);
  float4* efcrn = (float4*)(ws + off);   off += align16((size_t)E * 16);
  int* esrc = (int*)(ws + off);          off += align16((size_t)E * 4);
  int* cnt = (int*)(ws + off);           off += align16((size_t)N * 4);
  int* row_start = (int*)(ws + off);     off += align16((size_t)(N + 1) * 4);
  int* next = (int*)(ws + off);          off += align16((size_t)N * 4);
  float* erb = (float*)(ws + off);
  const size_t off_erb_end = off + (size_t)E * 20 * 4;
  unsigned int* tabB = (unsigned int*)(ws + off_erb_end);
  const size_t off_tabB_end = off_erb_end + (size_t)N * CC * 4;
  const int pre = (ws_size >= off_erb_end) ? 1 : 0;
  const int tb  = (pre && ws_size >= off_tabB_end) ? 1 : 0;

  hipMemsetAsync(cnt, 0, (size_t)N * sizeof(int), stream);

  detect_kernel<<<1, 64, 0, stream>>>(s, edges, flags);
  count_kernel<<<(E + 255) / 256, 256, 0, stream>>>(edges, cnt, flags, E);

  const int NB = (N + 4095) / 4096;
  if ((N % 4 == 0) && NB <= 64) {
    scan_part1<<<NB, 1024, 0, stream>>>(cnt, row_start, bsum, N);
    scan_part2<<<1, 64, 0, stream>>>(bsum, boff, row_start, NB, N);
    scan_part3<<<NB, 1024, 0, stream>>>(row_start, next, boff, N);
  } else {
    scan_kernel<<<1, 1024, 0, stream>>>(cnt, row_start, next, N);
  }

  if (pre)
    fill_kernel<1><<<(E + 255) / 256, 256, 0, stream>>>(edges, r_ij, rn, next,
                                                        esrc, efcrn, erb, flags, E);
  else
    fill_kernel<0><<<(E + 255) / 256, 256, 0, stream>>>(edges, r_ij, rn, next,
                                                        esrc, efcrn, erb, flags, E);
  prep_w_kernel<<<CC + NOUT, 128, 0, stream>>>(W1, W2, W1T, W2T, flags);
  node_mlp_mfma_kernel<<<(N + 63) / 64, 256, 0, stream>>>(s, v, W1T, W2T, b1, b2,
                                                          tabA, tabB, tb, flags, N);
  if (pre && tb)
    aggregate_kernel<1, 1><<<N, 128, 0, stream>>>(s, v, Wr, br, tabA, tabB,
                                                  row_start, esrc, efcrn, erb,
                                                  d_out, flags, N);
  else if (pre)
    aggregate_kernel<1, 0><<<N, 128, 0, stream>>>(s, v, Wr, br, tabA, tabB,
                                                  row_start, esrc, efcrn, erb,
                                                  d_out, flags, N);
  else
    aggregate_kernel<0, 0><<<N, 128, 0, stream>>>(s, v, Wr, br, tabA, tabB,
                                                  row_start, esrc, efcrn, erb,
                                                  d_out, flags, N);
}